// Round 6
// baseline (354.559 us; speedup 1.0000x reference)
//
#include <hip/hip_runtime.h>
#include <math.h>

#define HWSZ 4096
#define C_ 256
#define B_ 8

// ws layout (float offsets)
#define M_WS      0          // mask bf16: 8*256*4096 ushort = 4194304 floats
#define XB_WS     4194304    // x bf16 NHWC [b][hw][c]: 4194304 floats
#define WT2_WS    8388608    // (10*65536 + 9*32*256) ushort
#define SMEAN_WS  8753152    // 2048 (f channel sums)
#define SSCALE_WS 8755200    // 2048

typedef __attribute__((ext_vector_type(8))) short short8;
typedef __attribute__((ext_vector_type(4))) float f32x4;

__device__ __forceinline__ uint bfr(float a) {  // f32 -> bf16 bits (RNE)
  uint u = __float_as_uint(a);
  return (u + 0x7fffu + ((u >> 16) & 1u)) >> 16;
}
__device__ __forceinline__ uint pk2(float a, float b) { return bfr(a) | (bfr(b) << 16); }
__device__ __forceinline__ float bff(ushort u) { return __uint_as_float((uint)u << 16); }
__device__ __forceinline__ float lo16(uint u) { return __uint_as_float(u << 16); }
__device__ __forceinline__ float hi16(uint u) { return __uint_as_float(u & 0xffff0000u); }

// ---------------- k0: weights -> bf16 (+ zero smean) ----------------
__global__ __launch_bounds__(256) void k0_weights(
    const float* __restrict__ w_reg, const float* __restrict__ w_mask,
    const float* __restrict__ w_off, const float* __restrict__ w_mod,
    float* __restrict__ ws) {
  int i = blockIdx.x * 256 + threadIdx.x;
  const int nwt = 10 * 65536;
  const int total = nwt + 9 * 32 * 256;   // 729088
  if (i >= total) {
    int z = i - total;
    if (z < 2048) ws[SMEAN_WS + z] = 0.f;
    return;
  }
  float v;
  if (i < 9 * 65536) {
    int kk = i >> 16, o = (i >> 8) & 255, c = i & 255;
    v = w_reg[(o * C_ + c) * 9 + kk];
  } else if (i < nwt) {
    v = w_mask[i - 9 * 65536];
  } else {
    int e = i - nwt;
    int s = e >> 13, r = e & 8191;
    int o2 = r >> 8, c = r & 255;
    if (o2 < 18)      v = w_off[(o2 * C_ + c) * 9 + s];
    else if (o2 < 27) v = w_mod[((o2 - 18) * C_ + c) * 9 + s];
    else              v = 0.f;
  }
  ((ushort*)(ws + WT2_WS))[i] = (ushort)bfr(v);
}

// ---------------- k0b: x NCHW f32 -> NHWC bf16 ----------------
__global__ __launch_bounds__(256) void k0b_nhwc(const float* __restrict__ x,
                                                float* __restrict__ ws) {
  __shared__ float tile[64][65];
  int b = blockIdx.x >> 6, hw0 = (blockIdx.x & 63) << 6;
  int t = threadIdx.x;
  uint* xb = (uint*)(ws + XB_WS) + ((size_t)b << 19);
  int rr = t >> 6, cc = t & 63;
  int e = t & 7, hwp = t >> 3;
  for (int cg = 0; cg < 4; cg++) {
    __syncthreads();
    const float* xp = x + ((size_t)(b * 256 + cg * 64 + rr)) * HWSZ + hw0 + cc;
    #pragma unroll
    for (int r0 = 0; r0 < 64; r0 += 4)
      tile[r0 + rr][cc] = xp[(size_t)r0 * HWSZ];
    __syncthreads();
    #pragma unroll
    for (int h2 = 0; h2 < 2; h2++) {
      int hw_l = h2 * 32 + hwp;
      int c2 = e * 8;
      uint4 val;
      val.x = pk2(tile[c2][hw_l], tile[c2 + 1][hw_l]);
      val.y = pk2(tile[c2 + 2][hw_l], tile[c2 + 3][hw_l]);
      val.z = pk2(tile[c2 + 4][hw_l], tile[c2 + 5][hw_l]);
      val.w = pk2(tile[c2 + 6][hw_l], tile[c2 + 7][hw_l]);
      *(uint4*)&xb[(size_t)(hw0 + hw_l) * 128 + cg * 32 + e * 4] = val;
    }
  }
}

// ---------------- k2: fused kernel, n-split for occupancy ----------------
// block = 512 thr per (b, h, n-half): 32 positions x 256 o. LDS ~19.8 KB -> 4 blocks/CU.
// Round-4 tap structure: tight gather -> barrier -> GEMM, single vbuf.
__global__ __launch_bounds__(512, 8) void k2_fused(
    const float* __restrict__ b_off, const float* __restrict__ b_mod,
    const float* __restrict__ b_reg, const float* __restrict__ b_mask,
    float* __restrict__ ws, float* __restrict__ out) {
  __shared__ uint vbuf[32 * 128];      // 16 KB [n_local][128 uints] swizzled
  __shared__ float offmod[27 * 32];    // 3.4 KB

  int bl = ((blockIdx.x & 7) << 7) | (blockIdx.x >> 3);   // XCD k -> image k (1024 grid)
  int b = bl >> 7;
  int h = (bl >> 1) & 63;
  int n0 = (bl & 1) << 5;              // n-half base
  int t = threadIdx.x;
  int lane = t & 63, w = t >> 6;
  const int hwid = (w << 1) | (lane >> 5);   // half-wave id 0..15
  const int cl = lane & 31;                  // channel chunk (8 ch)
  const ushort* xb2 = (const ushort*)(ws + XB_WS) + ((size_t)b << 20);
  const ushort* wt2 = (const ushort*)(ws + WT2_WS);
  const ushort* wom = wt2 + 10 * 65536;
  const int fr = lane & 15, fq = lane >> 4;

  int nloc[2]; uint widx[2];
  #pragma unroll
  for (int p = 0; p < 2; p++) {
    nloc[p] = p * 16 + hwid;
    widx[p] = (uint)nloc[p] * 128u + (((uint)cl * 4u) ^ ((uint)(nloc[p] & 7) << 2));
  }

  auto makeRecs = [&](int kk, int p, float* wg, int* ix) {
    int nl = nloc[p];
    float dy = offmod[(2 * kk) * 32 + nl];
    float dx = offmod[(2 * kk + 1) * 32 + nl];
    float md = offmod[(18 + kk) * 32 + nl];
    float py = (float)(h + kk / 3 - 1) + dy;
    float px = (float)(n0 + nl + kk % 3 - 1) + dx;
    float fy = floorf(py), fx = floorf(px);
    float ly = py - fy, lx = px - fx;
    int y0 = (int)fy, x0 = (int)fx;
    int y1 = y0 + 1, x1 = x0 + 1;
    float vy0 = ((unsigned)y0 < 64u) ? 1.f : 0.f;
    float vy1 = ((unsigned)y1 < 64u) ? 1.f : 0.f;
    float vx0 = ((unsigned)x0 < 64u) ? 1.f : 0.f;
    float vx1 = ((unsigned)x1 < 64u) ? 1.f : 0.f;
    int cy0 = min(max(y0, 0), 63), cy1 = min(max(y1, 0), 63);
    int cx0 = min(max(x0, 0), 63), cx1 = min(max(x1, 0), 63);
    ix[0] = cy0 * 64 + cx0; wg[0] = (1.f - ly) * (1.f - lx) * md * vy0 * vx0;
    ix[1] = cy0 * 64 + cx1; wg[1] = (1.f - ly) * lx * md * vy0 * vx1;
    ix[2] = cy1 * 64 + cx0; wg[2] = ly * (1.f - lx) * md * vy1 * vx0;
    ix[3] = cy1 * 64 + cx1; wg[3] = ly * lx * md * vy1 * vx1;
  };
  auto combine = [&](const uint4* d, const float* wg) -> uint4 {
    float a0 = 0.f, a1 = 0.f, a2 = 0.f, a3 = 0.f, a4 = 0.f, a5 = 0.f, a6 = 0.f, a7 = 0.f;
    #pragma unroll
    for (int cr = 0; cr < 4; cr++) {
      uint4 dd = d[cr]; float wv = wg[cr];
      a0 = fmaf(wv, lo16(dd.x), a0); a1 = fmaf(wv, hi16(dd.x), a1);
      a2 = fmaf(wv, lo16(dd.y), a2); a3 = fmaf(wv, hi16(dd.y), a3);
      a4 = fmaf(wv, lo16(dd.z), a4); a5 = fmaf(wv, hi16(dd.z), a5);
      a6 = fmaf(wv, lo16(dd.w), a6); a7 = fmaf(wv, hi16(dd.w), a7);
    }
    return make_uint4(pk2(a0, a1), pk2(a2, a3), pk2(a4, a5), pk2(a6, a7));
  };

  // ======== Phase A: off/mod conv, 9 shifts (M=32 x N=32; waves 0..3 GEMM) ========
  f32x4 aom = (f32x4)0.f;
  const int mA = (w >> 1) & 1, ntA = w & 1;
  for (int s = 0; s < 9; s++) {
    int row = h + s / 3 - 1;
    uint4 pv[2];
    #pragma unroll
    for (int p = 0; p < 2; p++) {
      int col = n0 + nloc[p] + s % 3 - 1;
      uint4 v = make_uint4(0, 0, 0, 0);
      if (((unsigned)row < 64u) && ((unsigned)col < 64u))
        v = *(const uint4*)(xb2 + ((size_t)(row * 64 + col)) * 256 + cl * 8);
      pv[p] = v;
    }
    __syncthreads();   // prev GEMM done reading vbuf
    #pragma unroll
    for (int p = 0; p < 2; p++) *(uint4*)&vbuf[widx[p]] = pv[p];
    __syncthreads();
    if (w < 4) {
      const ushort* wp = wom + (size_t)s * 8192;
      for (int ks = 0; ks < 8; ks++) {
        short8 af = *(const short8*)(wp + (mA * 16 + fr) * 256 + ks * 32 + fq * 8);
        int bn = ntA * 16 + fr;
        uint idx = (uint)bn * 128u + (((uint)(ks * 16 + fq * 4)) ^ ((uint)(bn & 7) << 2));
        short8 bf = *(const short8*)&vbuf[idx];
        aom = __builtin_amdgcn_mfma_f32_16x16x32_bf16(af, bf, aom, 0, 0, 0);
      }
    }
  }
  __syncthreads();
  if (w < 4) {
    #pragma unroll
    for (int r = 0; r < 4; r++) {
      int o = mA * 16 + fq * 4 + r;
      int nn = ntA * 16 + fr;
      if (o < 18) {
        offmod[o * 32 + nn] = aom[r] + b_off[o];
      } else if (o < 27) {
        float v = aom[r] + b_mod[o - 18];
        offmod[o * 32 + nn] = 2.f / (1.f + expf(-v));
      }
    }
  }
  __syncthreads();

  // ======== Phase B: 9 deform taps + mask tap (round-4 structure) ========
  f32x4 acc[2][2];
  #pragma unroll
  for (int mt = 0; mt < 2; mt++)
    #pragma unroll
    for (int nt = 0; nt < 2; nt++) acc[mt][nt] = (f32x4)0.f;
  const int o0 = w << 5;
  float* sme = ws + SMEAN_WS + b * 256;
  ushort* mws = (ushort*)(ws + M_WS);

  for (int kk = 0; kk < 10; kk++) {
    uint4 pv[2];
    if (kk < 9) {
      #pragma unroll
      for (int p = 0; p < 2; p++) {
        float wg[4]; int ix[4];
        makeRecs(kk, p, wg, ix);
        uint4 d[4];
        #pragma unroll
        for (int cr = 0; cr < 4; cr++)
          d[cr] = *(const uint4*)(xb2 + (size_t)ix[cr] * 256 + cl * 8);
        pv[p] = combine(d, wg);
      }
    } else {
      #pragma unroll
      for (int p = 0; p < 2; p++)
        pv[p] = *(const uint4*)(xb2 + ((size_t)(h * 64 + n0 + nloc[p])) * 256 + cl * 8);
    }
    __syncthreads();   // prev GEMM done reading vbuf
    #pragma unroll
    for (int p = 0; p < 2; p++) *(uint4*)&vbuf[widx[p]] = pv[p];
    __syncthreads();
    const ushort* wtap = wt2 + (size_t)kk * 65536;
    for (int ks = 0; ks < 8; ks++) {
      short8 af0 = *(const short8*)(wtap + (o0 + fr) * 256 + ks * 32 + fq * 8);
      short8 af1 = *(const short8*)(wtap + (o0 + 16 + fr) * 256 + ks * 32 + fq * 8);
      #pragma unroll
      for (int nt = 0; nt < 2; nt++) {
        int bn = nt * 16 + fr;
        uint idx = (uint)bn * 128u + (((uint)(ks * 16 + fq * 4)) ^ ((uint)(bn & 7) << 2));
        short8 bf = *(const short8*)&vbuf[idx];
        acc[0][nt] = __builtin_amdgcn_mfma_f32_16x16x32_bf16(af0, bf, acc[0][nt], 0, 0, 0);
        acc[1][nt] = __builtin_amdgcn_mfma_f32_16x16x32_bf16(af1, bf, acc[1][nt], 0, 0, 0);
      }
    }
    // f epilogue after tap 8 (deform conv complete)
    if (kk == 8) {
      #pragma unroll
      for (int mt = 0; mt < 2; mt++)
        #pragma unroll
        for (int r = 0; r < 4; r++) {
          int o = o0 + mt * 16 + fq * 4 + r;
          float bo = b_reg[o];
          float* op = out + (size_t)(b * C_ + o) * HWSZ + h * 64 + n0;
          float so = 0.f;
          #pragma unroll
          for (int nt = 0; nt < 2; nt++) {
            float fv = acc[mt][nt][r] + bo;
            op[nt * 16 + fr] = fv;
            so += fv;
            acc[mt][nt][r] = 0.f;
          }
          so += __shfl_xor(so, 1);
          so += __shfl_xor(so, 2);
          so += __shfl_xor(so, 4);
          so += __shfl_xor(so, 8);
          if (fr == 0) atomicAdd(&sme[o], so);
        }
    }
  }

  // mask epilogue
  #pragma unroll
  for (int mt = 0; mt < 2; mt++)
    #pragma unroll
    for (int r = 0; r < 4; r++) {
      int o = o0 + mt * 16 + fq * 4 + r;
      float bm = b_mask[o];
      ushort* mp = mws + (size_t)(b * C_ + o) * HWSZ + h * 64 + n0;
      #pragma unroll
      for (int nt = 0; nt < 2; nt++) {
        float mv = fminf(fmaxf((acc[mt][nt][r] + bm) * (1.f / 6.f) + 0.5f, 0.f), 1.f);
        mp[nt * 16 + fr] = (ushort)bfr(mv);
      }
    }
}

// ---------------- k4: SE MLP (reads channel SUMS) ----------------
__global__ __launch_bounds__(256) void k4_se(
    const float* __restrict__ w_se1, const float* __restrict__ b_se1,
    const float* __restrict__ w_se2, const float* __restrict__ b_se2,
    float* __restrict__ ws) {
  __shared__ float sm[2048];
  __shared__ float s1[512];
  int t = threadIdx.x;
  for (int e = t; e < 2048; e += 256) sm[e] = ws[SMEAN_WS + e] * (1.f / HWSZ);
  __syncthreads();
  for (int e = t; e < 512; e += 256) {
    int b = e >> 6, cr = e & 63;
    float a = b_se1[cr];
    for (int c = 0; c < 256; c++) a += sm[b * 256 + c] * w_se1[cr * 256 + c];
    s1[e] = fmaxf(a, 0.f);
  }
  __syncthreads();
  for (int e = t; e < 2048; e += 256) {
    int b = e >> 8, c = e & 255;
    float a = b_se2[c];
    for (int cr = 0; cr < 64; cr++) a += s1[b * 64 + cr] * w_se2[c * 64 + cr];
    ws[SSCALE_WS + e] = 1.f / (1.f + expf(-a));
  }
}

// ---------------- k5: final combine: out = f*s*m + x ----------------
__global__ __launch_bounds__(256) void k5_final(const float* __restrict__ x,
                                                const float* __restrict__ ws,
                                                float* __restrict__ out) {
  const ushort* mws = (const ushort*)(ws + M_WS);
  int i4 = blockIdx.x * 256 + threadIdx.x;
  const int total = B_ * C_ * HWSZ / 4;
  for (; i4 < total; i4 += gridDim.x * 256) {
    int i = i4 * 4;
    int bc = i >> 12;
    float s = ws[SSCALE_WS + bc];
    float4 f = *(const float4*)&out[i];
    uint2 mu = *(const uint2*)&mws[i];
    float4 xv = *(const float4*)&x[i];
    float4 r;
    r.x = f.x * s * bff((ushort)(mu.x & 0xffffu)) + xv.x;
    r.y = f.y * s * bff((ushort)(mu.x >> 16)) + xv.y;
    r.z = f.z * s * bff((ushort)(mu.y & 0xffffu)) + xv.z;
    r.w = f.w * s * bff((ushort)(mu.y >> 16)) + xv.w;
    *(float4*)&out[i] = r;
  }
}

extern "C" void kernel_launch(void* const* d_in, const int* in_sizes, int n_in,
                              void* d_out, int out_size, void* d_ws, size_t ws_size,
                              hipStream_t stream) {
  const float* x      = (const float*)d_in[0];
  const float* w_off  = (const float*)d_in[1];
  const float* b_off  = (const float*)d_in[2];
  const float* w_mod  = (const float*)d_in[3];
  const float* b_mod  = (const float*)d_in[4];
  const float* w_reg  = (const float*)d_in[5];
  const float* b_reg  = (const float*)d_in[6];
  const float* w_se1  = (const float*)d_in[7];
  const float* b_se1  = (const float*)d_in[8];
  const float* w_se2  = (const float*)d_in[9];
  const float* b_se2  = (const float*)d_in[10];
  const float* w_mask = (const float*)d_in[11];
  const float* b_mask = (const float*)d_in[12];
  float* out = (float*)d_out;
  float* ws  = (float*)d_ws;

  k0_weights<<<dim3(2856), dim3(256), 0, stream>>>(w_reg, w_mask, w_off, w_mod, ws);
  k0b_nhwc<<<dim3(512), dim3(256), 0, stream>>>(x, ws);
  k2_fused<<<dim3(1024), dim3(512), 0, stream>>>(b_off, b_mod, b_reg, b_mask, ws, out);
  k4_se<<<dim3(1), dim3(256), 0, stream>>>(w_se1, b_se1, w_se2, b_se2, ws);
  k5_final<<<dim3(2048), dim3(256), 0, stream>>>(x, ws, out);
}

// Round 7
// 317.512 us; speedup vs baseline: 1.1167x; 1.1167x over previous
//
#include <hip/hip_runtime.h>
#include <math.h>

#define HWSZ 4096
#define C_ 256
#define B_ 8

// ws layout (float offsets)
#define M_WS      0          // mask bf16: 8*256*4096 ushort = 4194304 floats
#define XB_WS     4194304    // x bf16 NHWC [b][hw][c]: 4194304 floats
#define WT2_WS    8388608    // (10*65536 + 9*32*256) ushort
#define SMEAN_WS  8753152    // 2048 (f channel sums)
#define SSCALE_WS 8755200    // 2048

typedef __attribute__((ext_vector_type(8))) short short8;
typedef __attribute__((ext_vector_type(4))) float f32x4;

__device__ __forceinline__ uint bfr(float a) {  // f32 -> bf16 bits (RNE)
  uint u = __float_as_uint(a);
  return (u + 0x7fffu + ((u >> 16) & 1u)) >> 16;
}
__device__ __forceinline__ uint pk2(float a, float b) { return bfr(a) | (bfr(b) << 16); }
__device__ __forceinline__ float bff(ushort u) { return __uint_as_float((uint)u << 16); }
__device__ __forceinline__ float lo16(uint u) { return __uint_as_float(u << 16); }
__device__ __forceinline__ float hi16(uint u) { return __uint_as_float(u & 0xffff0000u); }

// ---------------- k0: weights -> bf16 (+ zero smean) ----------------
__global__ __launch_bounds__(256) void k0_weights(
    const float* __restrict__ w_reg, const float* __restrict__ w_mask,
    const float* __restrict__ w_off, const float* __restrict__ w_mod,
    float* __restrict__ ws) {
  int i = blockIdx.x * 256 + threadIdx.x;
  const int nwt = 10 * 65536;
  const int total = nwt + 9 * 32 * 256;   // 729088
  if (i >= total) {
    int z = i - total;
    if (z < 2048) ws[SMEAN_WS + z] = 0.f;
    return;
  }
  float v;
  if (i < 9 * 65536) {
    int kk = i >> 16, o = (i >> 8) & 255, c = i & 255;
    v = w_reg[(o * C_ + c) * 9 + kk];
  } else if (i < nwt) {
    v = w_mask[i - 9 * 65536];
  } else {
    int e = i - nwt;
    int s = e >> 13, r = e & 8191;
    int o2 = r >> 8, c = r & 255;
    if (o2 < 18)      v = w_off[(o2 * C_ + c) * 9 + s];
    else if (o2 < 27) v = w_mod[((o2 - 18) * C_ + c) * 9 + s];
    else              v = 0.f;
  }
  ((ushort*)(ws + WT2_WS))[i] = (ushort)bfr(v);
}

// ---------------- k0b: x NCHW f32 -> NHWC bf16 ----------------
__global__ __launch_bounds__(256) void k0b_nhwc(const float* __restrict__ x,
                                                float* __restrict__ ws) {
  __shared__ float tile[64][65];
  int b = blockIdx.x >> 6, hw0 = (blockIdx.x & 63) << 6;
  int t = threadIdx.x;
  uint* xb = (uint*)(ws + XB_WS) + ((size_t)b << 19);
  int rr = t >> 6, cc = t & 63;
  int e = t & 7, hwp = t >> 3;
  for (int cg = 0; cg < 4; cg++) {
    __syncthreads();
    const float* xp = x + ((size_t)(b * 256 + cg * 64 + rr)) * HWSZ + hw0 + cc;
    #pragma unroll
    for (int r0 = 0; r0 < 64; r0 += 4)
      tile[r0 + rr][cc] = xp[(size_t)r0 * HWSZ];
    __syncthreads();
    #pragma unroll
    for (int h2 = 0; h2 < 2; h2++) {
      int hw_l = h2 * 32 + hwp;
      int c2 = e * 8;
      uint4 val;
      val.x = pk2(tile[c2][hw_l], tile[c2 + 1][hw_l]);
      val.y = pk2(tile[c2 + 2][hw_l], tile[c2 + 3][hw_l]);
      val.z = pk2(tile[c2 + 4][hw_l], tile[c2 + 5][hw_l]);
      val.w = pk2(tile[c2 + 6][hw_l], tile[c2 + 7][hw_l]);
      *(uint4*)&xb[(size_t)(hw0 + hw_l) * 128 + cg * 32 + e * 4] = val;
    }
  }
}

// ---------------- k2: fused kernel, n-split, spill-free launch bounds ----------------
// block = 512 thr per (b, h, n-half): 32 positions x 256 o. LDS ~19.8 KB.
// (512,6): VGPR cap ~85 -> no spill (kernel needs ~64); 3 blocks/CU = 24 waves/CU.
__global__ __launch_bounds__(512, 6) void k2_fused(
    const float* __restrict__ b_off, const float* __restrict__ b_mod,
    const float* __restrict__ b_reg, const float* __restrict__ b_mask,
    float* __restrict__ ws, float* __restrict__ out) {
  __shared__ uint vbuf[32 * 128];      // 16 KB [n_local][128 uints] swizzled
  __shared__ float offmod[27 * 32];    // 3.4 KB

  int bl = ((blockIdx.x & 7) << 7) | (blockIdx.x >> 3);   // XCD k -> image k (1024 grid)
  int b = bl >> 7;
  int h = (bl >> 1) & 63;
  int n0 = (bl & 1) << 5;              // n-half base
  int t = threadIdx.x;
  int lane = t & 63, w = t >> 6;
  const int hwid = (w << 1) | (lane >> 5);   // half-wave id 0..15
  const int cl = lane & 31;                  // channel chunk (8 ch)
  const ushort* xb2 = (const ushort*)(ws + XB_WS) + ((size_t)b << 20);
  const ushort* wt2 = (const ushort*)(ws + WT2_WS);
  const ushort* wom = wt2 + 10 * 65536;
  const int fr = lane & 15, fq = lane >> 4;

  int nloc[2]; uint widx[2];
  #pragma unroll
  for (int p = 0; p < 2; p++) {
    nloc[p] = p * 16 + hwid;
    widx[p] = (uint)nloc[p] * 128u + (((uint)cl * 4u) ^ ((uint)(nloc[p] & 7) << 2));
  }

  auto makeRecs = [&](int kk, int p, float* wg, int* ix) {
    int nl = nloc[p];
    float dy = offmod[(2 * kk) * 32 + nl];
    float dx = offmod[(2 * kk + 1) * 32 + nl];
    float md = offmod[(18 + kk) * 32 + nl];
    float py = (float)(h + kk / 3 - 1) + dy;
    float px = (float)(n0 + nl + kk % 3 - 1) + dx;
    float fy = floorf(py), fx = floorf(px);
    float ly = py - fy, lx = px - fx;
    int y0 = (int)fy, x0 = (int)fx;
    int y1 = y0 + 1, x1 = x0 + 1;
    float vy0 = ((unsigned)y0 < 64u) ? 1.f : 0.f;
    float vy1 = ((unsigned)y1 < 64u) ? 1.f : 0.f;
    float vx0 = ((unsigned)x0 < 64u) ? 1.f : 0.f;
    float vx1 = ((unsigned)x1 < 64u) ? 1.f : 0.f;
    int cy0 = min(max(y0, 0), 63), cy1 = min(max(y1, 0), 63);
    int cx0 = min(max(x0, 0), 63), cx1 = min(max(x1, 0), 63);
    ix[0] = cy0 * 64 + cx0; wg[0] = (1.f - ly) * (1.f - lx) * md * vy0 * vx0;
    ix[1] = cy0 * 64 + cx1; wg[1] = (1.f - ly) * lx * md * vy0 * vx1;
    ix[2] = cy1 * 64 + cx0; wg[2] = ly * (1.f - lx) * md * vy1 * vx0;
    ix[3] = cy1 * 64 + cx1; wg[3] = ly * lx * md * vy1 * vx1;
  };
  auto combine = [&](const uint4* d, const float* wg) -> uint4 {
    float a0 = 0.f, a1 = 0.f, a2 = 0.f, a3 = 0.f, a4 = 0.f, a5 = 0.f, a6 = 0.f, a7 = 0.f;
    #pragma unroll
    for (int cr = 0; cr < 4; cr++) {
      uint4 dd = d[cr]; float wv = wg[cr];
      a0 = fmaf(wv, lo16(dd.x), a0); a1 = fmaf(wv, hi16(dd.x), a1);
      a2 = fmaf(wv, lo16(dd.y), a2); a3 = fmaf(wv, hi16(dd.y), a3);
      a4 = fmaf(wv, lo16(dd.z), a4); a5 = fmaf(wv, hi16(dd.z), a5);
      a6 = fmaf(wv, lo16(dd.w), a6); a7 = fmaf(wv, hi16(dd.w), a7);
    }
    return make_uint4(pk2(a0, a1), pk2(a2, a3), pk2(a4, a5), pk2(a6, a7));
  };

  // ======== Phase A: off/mod conv, 9 shifts (M=32 x N=32; waves 0..3 GEMM) ========
  f32x4 aom = (f32x4)0.f;
  const int mA = (w >> 1) & 1, ntA = w & 1;
  for (int s = 0; s < 9; s++) {
    int row = h + s / 3 - 1;
    uint4 pv[2];
    #pragma unroll
    for (int p = 0; p < 2; p++) {
      int col = n0 + nloc[p] + s % 3 - 1;
      uint4 v = make_uint4(0, 0, 0, 0);
      if (((unsigned)row < 64u) && ((unsigned)col < 64u))
        v = *(const uint4*)(xb2 + ((size_t)(row * 64 + col)) * 256 + cl * 8);
      pv[p] = v;
    }
    __syncthreads();   // prev GEMM done reading vbuf
    #pragma unroll
    for (int p = 0; p < 2; p++) *(uint4*)&vbuf[widx[p]] = pv[p];
    __syncthreads();
    if (w < 4) {
      const ushort* wp = wom + (size_t)s * 8192;
      for (int ks = 0; ks < 8; ks++) {
        short8 af = *(const short8*)(wp + (mA * 16 + fr) * 256 + ks * 32 + fq * 8);
        int bn = ntA * 16 + fr;
        uint idx = (uint)bn * 128u + (((uint)(ks * 16 + fq * 4)) ^ ((uint)(bn & 7) << 2));
        short8 bf = *(const short8*)&vbuf[idx];
        aom = __builtin_amdgcn_mfma_f32_16x16x32_bf16(af, bf, aom, 0, 0, 0);
      }
    }
  }
  __syncthreads();
  if (w < 4) {
    #pragma unroll
    for (int r = 0; r < 4; r++) {
      int o = mA * 16 + fq * 4 + r;
      int nn = ntA * 16 + fr;
      if (o < 18) {
        offmod[o * 32 + nn] = aom[r] + b_off[o];
      } else if (o < 27) {
        float v = aom[r] + b_mod[o - 18];
        offmod[o * 32 + nn] = 2.f / (1.f + expf(-v));
      }
    }
  }
  __syncthreads();

  // ======== Phase B: 9 deform taps + mask tap ========
  f32x4 acc[2][2];
  #pragma unroll
  for (int mt = 0; mt < 2; mt++)
    #pragma unroll
    for (int nt = 0; nt < 2; nt++) acc[mt][nt] = (f32x4)0.f;
  const int o0 = w << 5;
  float* sme = ws + SMEAN_WS + b * 256;
  ushort* mws = (ushort*)(ws + M_WS);

  for (int kk = 0; kk < 10; kk++) {
    uint4 pv[2];
    if (kk < 9) {
      #pragma unroll
      for (int p = 0; p < 2; p++) {
        float wg[4]; int ix[4];
        makeRecs(kk, p, wg, ix);
        uint4 d[4];
        #pragma unroll
        for (int cr = 0; cr < 4; cr++)
          d[cr] = *(const uint4*)(xb2 + (size_t)ix[cr] * 256 + cl * 8);
        pv[p] = combine(d, wg);
      }
    } else {
      #pragma unroll
      for (int p = 0; p < 2; p++)
        pv[p] = *(const uint4*)(xb2 + ((size_t)(h * 64 + n0 + nloc[p])) * 256 + cl * 8);
    }
    __syncthreads();   // prev GEMM done reading vbuf
    #pragma unroll
    for (int p = 0; p < 2; p++) *(uint4*)&vbuf[widx[p]] = pv[p];
    __syncthreads();
    const ushort* wtap = wt2 + (size_t)kk * 65536;
    for (int ks = 0; ks < 8; ks++) {
      short8 af0 = *(const short8*)(wtap + (o0 + fr) * 256 + ks * 32 + fq * 8);
      short8 af1 = *(const short8*)(wtap + (o0 + 16 + fr) * 256 + ks * 32 + fq * 8);
      #pragma unroll
      for (int nt = 0; nt < 2; nt++) {
        int bn = nt * 16 + fr;
        uint idx = (uint)bn * 128u + (((uint)(ks * 16 + fq * 4)) ^ ((uint)(bn & 7) << 2));
        short8 bf = *(const short8*)&vbuf[idx];
        acc[0][nt] = __builtin_amdgcn_mfma_f32_16x16x32_bf16(af0, bf, acc[0][nt], 0, 0, 0);
        acc[1][nt] = __builtin_amdgcn_mfma_f32_16x16x32_bf16(af1, bf, acc[1][nt], 0, 0, 0);
      }
    }
    // f epilogue after tap 8 (deform conv complete)
    if (kk == 8) {
      #pragma unroll
      for (int mt = 0; mt < 2; mt++)
        #pragma unroll
        for (int r = 0; r < 4; r++) {
          int o = o0 + mt * 16 + fq * 4 + r;
          float bo = b_reg[o];
          float* op = out + (size_t)(b * C_ + o) * HWSZ + h * 64 + n0;
          float so = 0.f;
          #pragma unroll
          for (int nt = 0; nt < 2; nt++) {
            float fv = acc[mt][nt][r] + bo;
            op[nt * 16 + fr] = fv;
            so += fv;
            acc[mt][nt][r] = 0.f;
          }
          so += __shfl_xor(so, 1);
          so += __shfl_xor(so, 2);
          so += __shfl_xor(so, 4);
          so += __shfl_xor(so, 8);
          if (fr == 0) atomicAdd(&sme[o], so);
        }
    }
  }

  // mask epilogue
  #pragma unroll
  for (int mt = 0; mt < 2; mt++)
    #pragma unroll
    for (int r = 0; r < 4; r++) {
      int o = o0 + mt * 16 + fq * 4 + r;
      float bm = b_mask[o];
      ushort* mp = mws + (size_t)(b * C_ + o) * HWSZ + h * 64 + n0;
      #pragma unroll
      for (int nt = 0; nt < 2; nt++) {
        float mv = fminf(fmaxf((acc[mt][nt][r] + bm) * (1.f / 6.f) + 0.5f, 0.f), 1.f);
        mp[nt * 16 + fr] = (ushort)bfr(mv);
      }
    }
}

// ---------------- k4: SE MLP (reads channel SUMS) ----------------
__global__ __launch_bounds__(256) void k4_se(
    const float* __restrict__ w_se1, const float* __restrict__ b_se1,
    const float* __restrict__ w_se2, const float* __restrict__ b_se2,
    float* __restrict__ ws) {
  __shared__ float sm[2048];
  __shared__ float s1[512];
  int t = threadIdx.x;
  for (int e = t; e < 2048; e += 256) sm[e] = ws[SMEAN_WS + e] * (1.f / HWSZ);
  __syncthreads();
  for (int e = t; e < 512; e += 256) {
    int b = e >> 6, cr = e & 63;
    float a = b_se1[cr];
    for (int c = 0; c < 256; c++) a += sm[b * 256 + c] * w_se1[cr * 256 + c];
    s1[e] = fmaxf(a, 0.f);
  }
  __syncthreads();
  for (int e = t; e < 2048; e += 256) {
    int b = e >> 8, c = e & 255;
    float a = b_se2[c];
    for (int cr = 0; cr < 64; cr++) a += s1[b * 64 + cr] * w_se2[c * 64 + cr];
    ws[SSCALE_WS + e] = 1.f / (1.f + expf(-a));
  }
}

// ---------------- k5: final combine: out = f*s*m + x ----------------
__global__ __launch_bounds__(256) void k5_final(const float* __restrict__ x,
                                                const float* __restrict__ ws,
                                                float* __restrict__ out) {
  const ushort* mws = (const ushort*)(ws + M_WS);
  int i4 = blockIdx.x * 256 + threadIdx.x;
  const int total = B_ * C_ * HWSZ / 4;
  for (; i4 < total; i4 += gridDim.x * 256) {
    int i = i4 * 4;
    int bc = i >> 12;
    float s = ws[SSCALE_WS + bc];
    float4 f = *(const float4*)&out[i];
    uint2 mu = *(const uint2*)&mws[i];
    float4 xv = *(const float4*)&x[i];
    float4 r;
    r.x = f.x * s * bff((ushort)(mu.x & 0xffffu)) + xv.x;
    r.y = f.y * s * bff((ushort)(mu.x >> 16)) + xv.y;
    r.z = f.z * s * bff((ushort)(mu.y & 0xffffu)) + xv.z;
    r.w = f.w * s * bff((ushort)(mu.y >> 16)) + xv.w;
    *(float4*)&out[i] = r;
  }
}

extern "C" void kernel_launch(void* const* d_in, const int* in_sizes, int n_in,
                              void* d_out, int out_size, void* d_ws, size_t ws_size,
                              hipStream_t stream) {
  const float* x      = (const float*)d_in[0];
  const float* w_off  = (const float*)d_in[1];
  const float* b_off  = (const float*)d_in[2];
  const float* w_mod  = (const float*)d_in[3];
  const float* b_mod  = (const float*)d_in[4];
  const float* w_reg  = (const float*)d_in[5];
  const float* b_reg  = (const float*)d_in[6];
  const float* w_se1  = (const float*)d_in[7];
  const float* b_se1  = (const float*)d_in[8];
  const float* w_se2  = (const float*)d_in[9];
  const float* b_se2  = (const float*)d_in[10];
  const float* w_mask = (const float*)d_in[11];
  const float* b_mask = (const float*)d_in[12];
  float* out = (float*)d_out;
  float* ws  = (float*)d_ws;

  k0_weights<<<dim3(2856), dim3(256), 0, stream>>>(w_reg, w_mask, w_off, w_mod, ws);
  k0b_nhwc<<<dim3(512), dim3(256), 0, stream>>>(x, ws);
  k2_fused<<<dim3(1024), dim3(512), 0, stream>>>(b_off, b_mod, b_reg, b_mask, ws, out);
  k4_se<<<dim3(1), dim3(256), 0, stream>>>(w_se1, b_se1, w_se2, b_se2, ws);
  k5_final<<<dim3(2048), dim3(256), 0, stream>>>(x, ws, out);
}

// Round 8
// 276.404 us; speedup vs baseline: 1.2828x; 1.1487x over previous
//
#include <hip/hip_runtime.h>
#include <math.h>

#define HWSZ 4096
#define C_ 256
#define B_ 8

// ws layout (float offsets)
#define M_WS      0          // mask bf16: 8*256*4096 ushort = 4194304 floats
#define XB_WS     4194304    // x bf16 NHWC [b][hw][c]: 4194304 floats
#define WT2_WS    8388608    // (10*65536 + 9*32*256) ushort
#define SMEAN_WS  8753152    // 2048 (f channel sums)
#define SSCALE_WS 8755200    // 2048

typedef __attribute__((ext_vector_type(8))) short short8;
typedef __attribute__((ext_vector_type(4))) float f32x4;

__device__ __forceinline__ uint bfr(float a) {  // f32 -> bf16 bits (RNE)
  uint u = __float_as_uint(a);
  return (u + 0x7fffu + ((u >> 16) & 1u)) >> 16;
}
__device__ __forceinline__ uint pk2(float a, float b) { return bfr(a) | (bfr(b) << 16); }
__device__ __forceinline__ float bff(ushort u) { return __uint_as_float((uint)u << 16); }
__device__ __forceinline__ float lo16(uint u) { return __uint_as_float(u << 16); }
__device__ __forceinline__ float hi16(uint u) { return __uint_as_float(u & 0xffff0000u); }

// ---------------- k0: weights -> bf16 (+ zero smean) ----------------
__global__ __launch_bounds__(256) void k0_weights(
    const float* __restrict__ w_reg, const float* __restrict__ w_mask,
    const float* __restrict__ w_off, const float* __restrict__ w_mod,
    float* __restrict__ ws) {
  int i = blockIdx.x * 256 + threadIdx.x;
  const int nwt = 10 * 65536;
  const int total = nwt + 9 * 32 * 256;   // 729088
  if (i >= total) {
    int z = i - total;
    if (z < 2048) ws[SMEAN_WS + z] = 0.f;
    return;
  }
  float v;
  if (i < 9 * 65536) {
    int kk = i >> 16, o = (i >> 8) & 255, c = i & 255;
    v = w_reg[(o * C_ + c) * 9 + kk];
  } else if (i < nwt) {
    v = w_mask[i - 9 * 65536];
  } else {
    int e = i - nwt;
    int s = e >> 13, r = e & 8191;
    int o2 = r >> 8, c = r & 255;
    if (o2 < 18)      v = w_off[(o2 * C_ + c) * 9 + s];
    else if (o2 < 27) v = w_mod[((o2 - 18) * C_ + c) * 9 + s];
    else              v = 0.f;
  }
  ((ushort*)(ws + WT2_WS))[i] = (ushort)bfr(v);
}

// ---------------- k0b: x NCHW f32 -> NHWC bf16 ----------------
__global__ __launch_bounds__(256) void k0b_nhwc(const float* __restrict__ x,
                                                float* __restrict__ ws) {
  __shared__ float tile[64][65];
  int b = blockIdx.x >> 6, hw0 = (blockIdx.x & 63) << 6;
  int t = threadIdx.x;
  uint* xb = (uint*)(ws + XB_WS) + ((size_t)b << 19);
  int rr = t >> 6, cc = t & 63;
  int e = t & 7, hwp = t >> 3;
  for (int cg = 0; cg < 4; cg++) {
    __syncthreads();
    const float* xp = x + ((size_t)(b * 256 + cg * 64 + rr)) * HWSZ + hw0 + cc;
    #pragma unroll
    for (int r0 = 0; r0 < 64; r0 += 4)
      tile[r0 + rr][cc] = xp[(size_t)r0 * HWSZ];
    __syncthreads();
    #pragma unroll
    for (int h2 = 0; h2 < 2; h2++) {
      int hw_l = h2 * 32 + hwp;
      int c2 = e * 8;
      uint4 val;
      val.x = pk2(tile[c2][hw_l], tile[c2 + 1][hw_l]);
      val.y = pk2(tile[c2 + 2][hw_l], tile[c2 + 3][hw_l]);
      val.z = pk2(tile[c2 + 4][hw_l], tile[c2 + 5][hw_l]);
      val.w = pk2(tile[c2 + 6][hw_l], tile[c2 + 7][hw_l]);
      *(uint4*)&xb[(size_t)(hw0 + hw_l) * 128 + cg * 32 + e * 4] = val;
    }
  }
}

// ---------------- k2: fused kernel, 4 waves x (64o x 64n), reg-recs, 4 blocks/CU ----------------
// block = 256 thr per (b,h): 64 positions x 256 o. LDS 38.75 KB -> 4 blocks/CU.
// Each wave reads vbuf once per tap (halves LDS-read traffic vs 8-wave round 4).
__global__ __launch_bounds__(256, 4) void k2_fused(
    const float* __restrict__ b_off, const float* __restrict__ b_mod,
    const float* __restrict__ b_reg, const float* __restrict__ b_mask,
    float* __restrict__ ws, float* __restrict__ out) {
  __shared__ uint vbuf[64 * 128];      // 32 KB [n][128 uints] swizzled
  __shared__ float offmod[27 * 64];    // 6.75 KB

  int bl = ((blockIdx.x & 7) << 6) | (blockIdx.x >> 3);   // XCD k -> image k (512 grid)
  int b = bl >> 6, h = bl & 63;
  int t = threadIdx.x;
  int lane = t & 63, w = t >> 6;             // wave 0..3
  const int hwid = t >> 5;                   // half-wave id 0..7
  const int cl = lane & 31;                  // channel chunk (8 ch)
  const ushort* xb2 = (const ushort*)(ws + XB_WS) + ((size_t)b << 20);
  const ushort* wt2 = (const ushort*)(ws + WT2_WS);
  const ushort* wom = wt2 + 10 * 65536;
  const int fr = lane & 15, fq = lane >> 4;

  int nloc[8]; uint widx[8];
  #pragma unroll
  for (int p = 0; p < 8; p++) {
    nloc[p] = p * 8 + hwid;
    widx[p] = (uint)nloc[p] * 128u + (((uint)cl * 4u) ^ ((uint)(nloc[p] & 7) << 2));
  }

  auto makeRecs = [&](int kk, int nl, float* wg, int* ix) {
    float dy = offmod[(2 * kk) * 64 + nl];
    float dx = offmod[(2 * kk + 1) * 64 + nl];
    float md = offmod[(18 + kk) * 64 + nl];
    float py = (float)(h + kk / 3 - 1) + dy;
    float px = (float)(nl + kk % 3 - 1) + dx;
    float fy = floorf(py), fx = floorf(px);
    float ly = py - fy, lx = px - fx;
    int y0 = (int)fy, x0 = (int)fx;
    int y1 = y0 + 1, x1 = x0 + 1;
    float vy0 = ((unsigned)y0 < 64u) ? 1.f : 0.f;
    float vy1 = ((unsigned)y1 < 64u) ? 1.f : 0.f;
    float vx0 = ((unsigned)x0 < 64u) ? 1.f : 0.f;
    float vx1 = ((unsigned)x1 < 64u) ? 1.f : 0.f;
    int cy0 = min(max(y0, 0), 63), cy1 = min(max(y1, 0), 63);
    int cx0 = min(max(x0, 0), 63), cx1 = min(max(x1, 0), 63);
    ix[0] = cy0 * 64 + cx0; wg[0] = (1.f - ly) * (1.f - lx) * md * vy0 * vx0;
    ix[1] = cy0 * 64 + cx1; wg[1] = (1.f - ly) * lx * md * vy0 * vx1;
    ix[2] = cy1 * 64 + cx0; wg[2] = ly * (1.f - lx) * md * vy1 * vx0;
    ix[3] = cy1 * 64 + cx1; wg[3] = ly * lx * md * vy1 * vx1;
  };
  auto combine = [&](const uint4* d, const float* wg) -> uint4 {
    float a0 = 0.f, a1 = 0.f, a2 = 0.f, a3 = 0.f, a4 = 0.f, a5 = 0.f, a6 = 0.f, a7 = 0.f;
    #pragma unroll
    for (int cr = 0; cr < 4; cr++) {
      uint4 dd = d[cr]; float wv = wg[cr];
      a0 = fmaf(wv, lo16(dd.x), a0); a1 = fmaf(wv, hi16(dd.x), a1);
      a2 = fmaf(wv, lo16(dd.y), a2); a3 = fmaf(wv, hi16(dd.y), a3);
      a4 = fmaf(wv, lo16(dd.z), a4); a5 = fmaf(wv, hi16(dd.z), a5);
      a6 = fmaf(wv, lo16(dd.w), a6); a7 = fmaf(wv, hi16(dd.w), a7);
    }
    return make_uint4(pk2(a0, a1), pk2(a2, a3), pk2(a4, a5), pk2(a6, a7));
  };

  // ======== Phase A: off/mod conv, 9 shifts. Wave w = n-tile w; m-tiles 0,1 both. ========
  f32x4 aomA = (f32x4)0.f, aomB = (f32x4)0.f;
  for (int s = 0; s < 9; s++) {
    int row = h + s / 3 - 1;
    uint4 pv[8];
    #pragma unroll
    for (int p = 0; p < 8; p++) {
      int col = nloc[p] + s % 3 - 1;
      uint4 v = make_uint4(0, 0, 0, 0);
      if (((unsigned)row < 64u) && ((unsigned)col < 64u))
        v = *(const uint4*)(xb2 + ((size_t)(row * 64 + col)) * 256 + cl * 8);
      pv[p] = v;
    }
    __syncthreads();   // prev GEMM done reading vbuf
    #pragma unroll
    for (int p = 0; p < 8; p++) *(uint4*)&vbuf[widx[p]] = pv[p];
    __syncthreads();
    const ushort* wp = wom + (size_t)s * 8192;
    for (int ks = 0; ks < 8; ks++) {
      short8 af0 = *(const short8*)(wp + fr * 256 + ks * 32 + fq * 8);
      short8 af1 = *(const short8*)(wp + (16 + fr) * 256 + ks * 32 + fq * 8);
      int bn = w * 16 + fr;
      uint idx = (uint)bn * 128u + (((uint)(ks * 16 + fq * 4)) ^ ((uint)(bn & 7) << 2));
      short8 bf = *(const short8*)&vbuf[idx];
      aomA = __builtin_amdgcn_mfma_f32_16x16x32_bf16(af0, bf, aomA, 0, 0, 0);
      aomB = __builtin_amdgcn_mfma_f32_16x16x32_bf16(af1, bf, aomB, 0, 0, 0);
    }
  }
  __syncthreads();
  #pragma unroll
  for (int r = 0; r < 4; r++) {
    int nn = w * 16 + fr;
    int oA = fq * 4 + r;          // m-tile 0: o2 0..15 (all offsets)
    offmod[oA * 64 + nn] = aomA[r] + b_off[oA];
    int oB = 16 + fq * 4 + r;     // m-tile 1: o2 16..31
    if (oB < 18) {
      offmod[oB * 64 + nn] = aomB[r] + b_off[oB];
    } else if (oB < 27) {
      float v = aomB[r] + b_mod[oB - 18];
      offmod[oB * 64 + nn] = 2.f / (1.f + expf(-v));
    }
  }
  __syncthreads();

  // ======== Phase B: 9 deform taps + mask tap ========
  f32x4 acc[4][4];
  #pragma unroll
  for (int mt = 0; mt < 4; mt++)
    #pragma unroll
    for (int nt = 0; nt < 4; nt++) acc[mt][nt] = (f32x4)0.f;
  const int o0 = w << 6;
  float* sme = ws + SMEAN_WS + b * 256;
  ushort* mws = (ushort*)(ws + M_WS);

  for (int kk = 0; kk < 10; kk++) {
    uint4 pv[8];
    if (kk < 9) {
      #pragma unroll
      for (int p = 0; p < 8; p++) {
        float wg[4]; int ix[4];
        makeRecs(kk, nloc[p], wg, ix);
        uint4 d[4];
        #pragma unroll
        for (int cr = 0; cr < 4; cr++)
          d[cr] = *(const uint4*)(xb2 + (size_t)ix[cr] * 256 + cl * 8);
        pv[p] = combine(d, wg);
      }
    } else {
      #pragma unroll
      for (int p = 0; p < 8; p++)
        pv[p] = *(const uint4*)(xb2 + ((size_t)(h * 64 + nloc[p])) * 256 + cl * 8);
    }
    __syncthreads();   // prev GEMM done reading vbuf
    #pragma unroll
    for (int p = 0; p < 8; p++) *(uint4*)&vbuf[widx[p]] = pv[p];
    __syncthreads();
    const ushort* wtap = wt2 + (size_t)kk * 65536;
    for (int ks = 0; ks < 8; ks++) {
      short8 af[4];
      #pragma unroll
      for (int mt = 0; mt < 4; mt++)
        af[mt] = *(const short8*)(wtap + (o0 + mt * 16 + fr) * 256 + ks * 32 + fq * 8);
      #pragma unroll
      for (int nt = 0; nt < 4; nt++) {
        int bn = nt * 16 + fr;
        uint idx = (uint)bn * 128u + (((uint)(ks * 16 + fq * 4)) ^ ((uint)(bn & 7) << 2));
        short8 bf = *(const short8*)&vbuf[idx];
        #pragma unroll
        for (int mt = 0; mt < 4; mt++)
          acc[mt][nt] = __builtin_amdgcn_mfma_f32_16x16x32_bf16(af[mt], bf, acc[mt][nt], 0, 0, 0);
      }
    }
    // f epilogue after tap 8 (deform conv complete)
    if (kk == 8) {
      #pragma unroll
      for (int mt = 0; mt < 4; mt++)
        #pragma unroll
        for (int r = 0; r < 4; r++) {
          int o = o0 + mt * 16 + fq * 4 + r;
          float bo = b_reg[o];
          float* op = out + (size_t)(b * C_ + o) * HWSZ + h * 64;
          float so = 0.f;
          #pragma unroll
          for (int nt = 0; nt < 4; nt++) {
            float fv = acc[mt][nt][r] + bo;
            op[nt * 16 + fr] = fv;
            so += fv;
            acc[mt][nt][r] = 0.f;
          }
          so += __shfl_xor(so, 1);
          so += __shfl_xor(so, 2);
          so += __shfl_xor(so, 4);
          so += __shfl_xor(so, 8);
          if (fr == 0) atomicAdd(&sme[o], so);
        }
    }
  }

  // mask epilogue
  #pragma unroll
  for (int mt = 0; mt < 4; mt++)
    #pragma unroll
    for (int r = 0; r < 4; r++) {
      int o = o0 + mt * 16 + fq * 4 + r;
      float bm = b_mask[o];
      ushort* mp = mws + (size_t)(b * C_ + o) * HWSZ + h * 64;
      #pragma unroll
      for (int nt = 0; nt < 4; nt++) {
        float mv = fminf(fmaxf((acc[mt][nt][r] + bm) * (1.f / 6.f) + 0.5f, 0.f), 1.f);
        mp[nt * 16 + fr] = (ushort)bfr(mv);
      }
    }
}

// ---------------- k4: SE MLP (reads channel SUMS) ----------------
__global__ __launch_bounds__(256) void k4_se(
    const float* __restrict__ w_se1, const float* __restrict__ b_se1,
    const float* __restrict__ w_se2, const float* __restrict__ b_se2,
    float* __restrict__ ws) {
  __shared__ float sm[2048];
  __shared__ float s1[512];
  int t = threadIdx.x;
  for (int e = t; e < 2048; e += 256) sm[e] = ws[SMEAN_WS + e] * (1.f / HWSZ);
  __syncthreads();
  for (int e = t; e < 512; e += 256) {
    int b = e >> 6, cr = e & 63;
    float a = b_se1[cr];
    for (int c = 0; c < 256; c++) a += sm[b * 256 + c] * w_se1[cr * 256 + c];
    s1[e] = fmaxf(a, 0.f);
  }
  __syncthreads();
  for (int e = t; e < 2048; e += 256) {
    int b = e >> 8, c = e & 255;
    float a = b_se2[c];
    for (int cr = 0; cr < 64; cr++) a += s1[b * 64 + cr] * w_se2[c * 64 + cr];
    ws[SSCALE_WS + e] = 1.f / (1.f + expf(-a));
  }
}

// ---------------- k5: final combine: out = f*s*m + x ----------------
__global__ __launch_bounds__(256) void k5_final(const float* __restrict__ x,
                                                const float* __restrict__ ws,
                                                float* __restrict__ out) {
  const ushort* mws = (const ushort*)(ws + M_WS);
  int i4 = blockIdx.x * 256 + threadIdx.x;
  const int total = B_ * C_ * HWSZ / 4;
  for (; i4 < total; i4 += gridDim.x * 256) {
    int i = i4 * 4;
    int bc = i >> 12;
    float s = ws[SSCALE_WS + bc];
    float4 f = *(const float4*)&out[i];
    uint2 mu = *(const uint2*)&mws[i];
    float4 xv = *(const float4*)&x[i];
    float4 r;
    r.x = f.x * s * bff((ushort)(mu.x & 0xffffu)) + xv.x;
    r.y = f.y * s * bff((ushort)(mu.x >> 16)) + xv.y;
    r.z = f.z * s * bff((ushort)(mu.y & 0xffffu)) + xv.z;
    r.w = f.w * s * bff((ushort)(mu.y >> 16)) + xv.w;
    *(float4*)&out[i] = r;
  }
}

extern "C" void kernel_launch(void* const* d_in, const int* in_sizes, int n_in,
                              void* d_out, int out_size, void* d_ws, size_t ws_size,
                              hipStream_t stream) {
  const float* x      = (const float*)d_in[0];
  const float* w_off  = (const float*)d_in[1];
  const float* b_off  = (const float*)d_in[2];
  const float* w_mod  = (const float*)d_in[3];
  const float* b_mod  = (const float*)d_in[4];
  const float* w_reg  = (const float*)d_in[5];
  const float* b_reg  = (const float*)d_in[6];
  const float* w_se1  = (const float*)d_in[7];
  const float* b_se1  = (const float*)d_in[8];
  const float* w_se2  = (const float*)d_in[9];
  const float* b_se2  = (const float*)d_in[10];
  const float* w_mask = (const float*)d_in[11];
  const float* b_mask = (const float*)d_in[12];
  float* out = (float*)d_out;
  float* ws  = (float*)d_ws;

  k0_weights<<<dim3(2856), dim3(256), 0, stream>>>(w_reg, w_mask, w_off, w_mod, ws);
  k0b_nhwc<<<dim3(512), dim3(256), 0, stream>>>(x, ws);
  k2_fused<<<dim3(512), dim3(256), 0, stream>>>(b_off, b_mod, b_reg, b_mask, ws, out);
  k4_se<<<dim3(1), dim3(256), 0, stream>>>(w_se1, b_se1, w_se2, b_se2, ws);
  k5_final<<<dim3(2048), dim3(256), 0, stream>>>(x, ws, out);
}

// Round 9
// 239.016 us; speedup vs baseline: 1.4834x; 1.1564x over previous
//
#include <hip/hip_runtime.h>
#include <math.h>

#define HWSZ 4096
#define C_ 256
#define B_ 8

// ws layout (float offsets)
#define M_WS      0          // mask bf16: 8*256*4096 ushort = 4194304 floats
#define XB_WS     4194304    // x bf16 NHWC [b][hw][c]: 4194304 floats
#define WT2_WS    8388608    // (10*65536 + 9*32*256) ushort
#define SMEAN_WS  8753152    // 2048 (f channel sums)
#define SSCALE_WS 8755200    // 2048

typedef __attribute__((ext_vector_type(8))) short short8;
typedef __attribute__((ext_vector_type(4))) float f32x4;

__device__ __forceinline__ uint bfr(float a) {  // f32 -> bf16 bits (RNE)
  uint u = __float_as_uint(a);
  return (u + 0x7fffu + ((u >> 16) & 1u)) >> 16;
}
__device__ __forceinline__ uint pk2(float a, float b) { return bfr(a) | (bfr(b) << 16); }
__device__ __forceinline__ float bff(ushort u) { return __uint_as_float((uint)u << 16); }
__device__ __forceinline__ float lo16(uint u) { return __uint_as_float(u << 16); }
__device__ __forceinline__ float hi16(uint u) { return __uint_as_float(u & 0xffff0000u); }

// ---------------- k0: weights -> bf16 (+ zero smean) ----------------
__global__ __launch_bounds__(256) void k0_weights(
    const float* __restrict__ w_reg, const float* __restrict__ w_mask,
    const float* __restrict__ w_off, const float* __restrict__ w_mod,
    float* __restrict__ ws) {
  int i = blockIdx.x * 256 + threadIdx.x;
  const int nwt = 10 * 65536;
  const int total = nwt + 9 * 32 * 256;   // 729088
  if (i >= total) {
    int z = i - total;
    if (z < 2048) ws[SMEAN_WS + z] = 0.f;
    return;
  }
  float v;
  if (i < 9 * 65536) {
    int kk = i >> 16, o = (i >> 8) & 255, c = i & 255;
    v = w_reg[(o * C_ + c) * 9 + kk];
  } else if (i < nwt) {
    v = w_mask[i - 9 * 65536];
  } else {
    int e = i - nwt;
    int s = e >> 13, r = e & 8191;
    int o2 = r >> 8, c = r & 255;
    if (o2 < 18)      v = w_off[(o2 * C_ + c) * 9 + s];
    else if (o2 < 27) v = w_mod[((o2 - 18) * C_ + c) * 9 + s];
    else              v = 0.f;
  }
  ((ushort*)(ws + WT2_WS))[i] = (ushort)bfr(v);
}

// ---------------- k0b: x NCHW f32 -> NHWC bf16 ----------------
__global__ __launch_bounds__(256) void k0b_nhwc(const float* __restrict__ x,
                                                float* __restrict__ ws) {
  __shared__ float tile[64][65];
  int b = blockIdx.x >> 6, hw0 = (blockIdx.x & 63) << 6;
  int t = threadIdx.x;
  uint* xb = (uint*)(ws + XB_WS) + ((size_t)b << 19);
  int rr = t >> 6, cc = t & 63;
  int e = t & 7, hwp = t >> 3;
  for (int cg = 0; cg < 4; cg++) {
    __syncthreads();
    const float* xp = x + ((size_t)(b * 256 + cg * 64 + rr)) * HWSZ + hw0 + cc;
    #pragma unroll
    for (int r0 = 0; r0 < 64; r0 += 4)
      tile[r0 + rr][cc] = xp[(size_t)r0 * HWSZ];
    __syncthreads();
    #pragma unroll
    for (int h2 = 0; h2 < 2; h2++) {
      int hw_l = h2 * 32 + hwp;
      int c2 = e * 8;
      uint4 val;
      val.x = pk2(tile[c2][hw_l], tile[c2 + 1][hw_l]);
      val.y = pk2(tile[c2 + 2][hw_l], tile[c2 + 3][hw_l]);
      val.z = pk2(tile[c2 + 4][hw_l], tile[c2 + 5][hw_l]);
      val.w = pk2(tile[c2 + 6][hw_l], tile[c2 + 7][hw_l]);
      *(uint4*)&xb[(size_t)(hw0 + hw_l) * 128 + cg * 32 + e * 4] = val;
    }
  }
}

// ---------------- k2: producer/consumer wave-specialized fused kernel ----------------
// 512 thr per (b,h): waves 0-3 produce (gather tap k+1 -> vb[nxt]),
// waves 4-7 consume (GEMM tap k from vb[cur], 64o x 64n each). 1 barrier/tap.
__global__ __launch_bounds__(512, 4) void k2_fused(
    const float* __restrict__ b_off, const float* __restrict__ b_mod,
    const float* __restrict__ b_reg, const float* __restrict__ b_mask,
    float* __restrict__ ws, float* __restrict__ out) {
  __shared__ uint vb[2][64 * 128];     // 2 x 32 KB
  __shared__ float offmod[27 * 64];    // 6.75 KB

  int bl = ((blockIdx.x & 7) << 6) | (blockIdx.x >> 3);   // XCD k -> image k
  int b = bl >> 6, h = bl & 63;
  int t = threadIdx.x;
  int lane = t & 63, w = t >> 6;
  const bool producer = (w < 4);
  const int cw = w & 3;                      // role-local wave id
  const int cl = lane & 31;                  // channel chunk (8 ch)
  const int fr = lane & 15, fq = lane >> 4;
  const int hw16 = t >> 5;                   // all-wave half-wave id (prologues, t<512 -> 0..15)
  const int hw8 = (cw << 1) | (lane >> 5);   // producer half-wave id 0..7
  const ushort* xb2 = (const ushort*)(ws + XB_WS) + ((size_t)b << 20);
  const ushort* wt2 = (const ushort*)(ws + WT2_WS);
  const ushort* wom = wt2 + 10 * 65536;

  auto widx = [&](int n) -> uint {
    return (uint)n * 128u + (((uint)cl * 4u) ^ ((uint)(n & 7) << 2));
  };
  auto makeRecs = [&](int kk, int nl, float* wg, int* ix) {
    float dy = offmod[(2 * kk) * 64 + nl];
    float dx = offmod[(2 * kk + 1) * 64 + nl];
    float md = offmod[(18 + kk) * 64 + nl];
    float py = (float)(h + kk / 3 - 1) + dy;
    float px = (float)(nl + kk % 3 - 1) + dx;
    float fy = floorf(py), fx = floorf(px);
    float ly = py - fy, lx = px - fx;
    int y0 = (int)fy, x0 = (int)fx;
    int y1 = y0 + 1, x1 = x0 + 1;
    float vy0 = ((unsigned)y0 < 64u) ? 1.f : 0.f;
    float vy1 = ((unsigned)y1 < 64u) ? 1.f : 0.f;
    float vx0 = ((unsigned)x0 < 64u) ? 1.f : 0.f;
    float vx1 = ((unsigned)x1 < 64u) ? 1.f : 0.f;
    int cy0 = min(max(y0, 0), 63), cy1 = min(max(y1, 0), 63);
    int cx0 = min(max(x0, 0), 63), cx1 = min(max(x1, 0), 63);
    ix[0] = cy0 * 64 + cx0; wg[0] = (1.f - ly) * (1.f - lx) * md * vy0 * vx0;
    ix[1] = cy0 * 64 + cx1; wg[1] = (1.f - ly) * lx * md * vy0 * vx1;
    ix[2] = cy1 * 64 + cx0; wg[2] = ly * (1.f - lx) * md * vy1 * vx0;
    ix[3] = cy1 * 64 + cx1; wg[3] = ly * lx * md * vy1 * vx1;
  };
  auto combine = [&](const uint4* d, const float* wg) -> uint4 {
    float a0 = 0.f, a1 = 0.f, a2 = 0.f, a3 = 0.f, a4 = 0.f, a5 = 0.f, a6 = 0.f, a7 = 0.f;
    #pragma unroll
    for (int cr = 0; cr < 4; cr++) {
      uint4 dd = d[cr]; float wv = wg[cr];
      a0 = fmaf(wv, lo16(dd.x), a0); a1 = fmaf(wv, hi16(dd.x), a1);
      a2 = fmaf(wv, lo16(dd.y), a2); a3 = fmaf(wv, hi16(dd.y), a3);
      a4 = fmaf(wv, lo16(dd.z), a4); a5 = fmaf(wv, hi16(dd.z), a5);
      a6 = fmaf(wv, lo16(dd.w), a6); a7 = fmaf(wv, hi16(dd.w), a7);
    }
    return make_uint4(pk2(a0, a1), pk2(a2, a3), pk2(a4, a5), pk2(a6, a7));
  };
  auto loadPlain = [&](int row, int col) -> uint4 {
    uint4 v = make_uint4(0, 0, 0, 0);
    if (((unsigned)row < 64u) && ((unsigned)col < 64u))
      v = *(const uint4*)(xb2 + ((size_t)(row * 64 + col)) * 256 + cl * 8);
    return v;
  };

  // ======== Phase A: off/mod conv, 9 shifts, producer/consumer ========
  // prologue: ALL waves fill shift 0 -> vb[0]
  #pragma unroll
  for (int p = 0; p < 4; p++) {
    int n = p * 16 + hw16;
    uint4 v = loadPlain(h - 1, n - 1);
    *(uint4*)&vb[0][widx(n)] = v;
  }
  __syncthreads();
  f32x4 aomA = (f32x4)0.f, aomB = (f32x4)0.f;
  for (int s = 0; s < 9; s++) {
    if (producer) {
      if (s < 8) {
        int row = h + (s + 1) / 3 - 1;
        #pragma unroll 2
        for (int p = 0; p < 8; p++) {
          int n = p * 8 + hw8;
          uint4 v = loadPlain(row, n + (s + 1) % 3 - 1);
          *(uint4*)&vb[(s + 1) & 1][widx(n)] = v;
        }
      }
    } else {
      const ushort* wp = wom + (size_t)s * 8192;
      const uint cur = s & 1;
      for (int ks = 0; ks < 8; ks++) {
        short8 af0 = *(const short8*)(wp + fr * 256 + ks * 32 + fq * 8);
        short8 af1 = *(const short8*)(wp + (16 + fr) * 256 + ks * 32 + fq * 8);
        int bn = cw * 16 + fr;
        uint idx = (uint)bn * 128u + (((uint)(ks * 16 + fq * 4)) ^ ((uint)(bn & 7) << 2));
        short8 bf = *(const short8*)&vb[cur][idx];
        aomA = __builtin_amdgcn_mfma_f32_16x16x32_bf16(af0, bf, aomA, 0, 0, 0);
        aomB = __builtin_amdgcn_mfma_f32_16x16x32_bf16(af1, bf, aomB, 0, 0, 0);
      }
    }
    __syncthreads();
  }
  if (!producer) {
    #pragma unroll
    for (int r = 0; r < 4; r++) {
      int nn = cw * 16 + fr;
      int oA = fq * 4 + r;
      offmod[oA * 64 + nn] = aomA[r] + b_off[oA];
      int oB = 16 + fq * 4 + r;
      if (oB < 18) {
        offmod[oB * 64 + nn] = aomB[r] + b_off[oB];
      } else if (oB < 27) {
        float v = aomB[r] + b_mod[oB - 18];
        offmod[oB * 64 + nn] = 2.f / (1.f + expf(-v));
      }
    }
  }
  __syncthreads();

  // ======== Phase B prologue: ALL waves gather tap 0 -> vb[0] ========
  #pragma unroll
  for (int p = 0; p < 4; p++) {
    int n = p * 16 + hw16;
    float wg[4]; int ix[4];
    makeRecs(0, n, wg, ix);
    uint4 d[4];
    #pragma unroll
    for (int cr = 0; cr < 4; cr++)
      d[cr] = *(const uint4*)(xb2 + (size_t)ix[cr] * 256 + cl * 8);
    *(uint4*)&vb[0][widx(n)] = combine(d, wg);
  }
  __syncthreads();

  // ======== Phase B: 9 deform taps + mask tap ========
  f32x4 acc[4][4];
  #pragma unroll
  for (int mt = 0; mt < 4; mt++)
    #pragma unroll
    for (int nt = 0; nt < 4; nt++) acc[mt][nt] = (f32x4)0.f;
  const int o0 = cw << 6;
  float* sme = ws + SMEAN_WS + b * 256;
  ushort* mws = (ushort*)(ws + M_WS);

  for (int kk = 0; kk < 10; kk++) {
    const uint nxt = (kk & 1) ^ 1;
    if (producer) {
      if (kk < 8) {          // prefetch deform tap kk+1
        #pragma unroll 2
        for (int p = 0; p < 8; p++) {
          int n = p * 8 + hw8;
          float wg[4]; int ix[4];
          makeRecs(kk + 1, n, wg, ix);
          uint4 d[4];
          #pragma unroll
          for (int cr = 0; cr < 4; cr++)
            d[cr] = *(const uint4*)(xb2 + (size_t)ix[cr] * 256 + cl * 8);
          *(uint4*)&vb[nxt][widx(n)] = combine(d, wg);
        }
      } else if (kk == 8) {  // prefetch mask tap (plain row)
        #pragma unroll 2
        for (int p = 0; p < 8; p++) {
          int n = p * 8 + hw8;
          uint4 v = *(const uint4*)(xb2 + ((size_t)(h * 64 + n)) * 256 + cl * 8);
          *(uint4*)&vb[nxt][widx(n)] = v;
        }
      }
    } else {
      const uint cur = kk & 1;
      const ushort* wtap = wt2 + (size_t)kk * 65536;
      for (int ks = 0; ks < 8; ks++) {
        short8 af[4];
        #pragma unroll
        for (int mt = 0; mt < 4; mt++)
          af[mt] = *(const short8*)(wtap + (o0 + mt * 16 + fr) * 256 + ks * 32 + fq * 8);
        #pragma unroll
        for (int nt = 0; nt < 4; nt++) {
          int bn = nt * 16 + fr;
          uint idx = (uint)bn * 128u + (((uint)(ks * 16 + fq * 4)) ^ ((uint)(bn & 7) << 2));
          short8 bf = *(const short8*)&vb[cur][idx];
          #pragma unroll
          for (int mt = 0; mt < 4; mt++)
            acc[mt][nt] = __builtin_amdgcn_mfma_f32_16x16x32_bf16(af[mt], bf, acc[mt][nt], 0, 0, 0);
        }
      }
      if (kk == 8) {   // f epilogue (deform conv complete); overlaps producers' mask gather
        #pragma unroll
        for (int mt = 0; mt < 4; mt++)
          #pragma unroll
          for (int r = 0; r < 4; r++) {
            int o = o0 + mt * 16 + fq * 4 + r;
            float bo = b_reg[o];
            float* op = out + (size_t)(b * C_ + o) * HWSZ + h * 64;
            float so = 0.f;
            #pragma unroll
            for (int nt = 0; nt < 4; nt++) {
              float fv = acc[mt][nt][r] + bo;
              op[nt * 16 + fr] = fv;
              so += fv;
              acc[mt][nt][r] = 0.f;
            }
            so += __shfl_xor(so, 1);
            so += __shfl_xor(so, 2);
            so += __shfl_xor(so, 4);
            so += __shfl_xor(so, 8);
            if (fr == 0) atomicAdd(&sme[o], so);
          }
      }
    }
    __syncthreads();
  }

  // mask epilogue (consumers)
  if (!producer) {
    #pragma unroll
    for (int mt = 0; mt < 4; mt++)
      #pragma unroll
      for (int r = 0; r < 4; r++) {
        int o = o0 + mt * 16 + fq * 4 + r;
        float bm = b_mask[o];
        ushort* mp = mws + (size_t)(b * C_ + o) * HWSZ + h * 64;
        #pragma unroll
        for (int nt = 0; nt < 4; nt++) {
          float mv = fminf(fmaxf((acc[mt][nt][r] + bm) * (1.f / 6.f) + 0.5f, 0.f), 1.f);
          mp[nt * 16 + fr] = (ushort)bfr(mv);
        }
      }
  }
}

// ---------------- k4: SE MLP (reads channel SUMS) ----------------
__global__ __launch_bounds__(256) void k4_se(
    const float* __restrict__ w_se1, const float* __restrict__ b_se1,
    const float* __restrict__ w_se2, const float* __restrict__ b_se2,
    float* __restrict__ ws) {
  __shared__ float sm[2048];
  __shared__ float s1[512];
  int t = threadIdx.x;
  for (int e = t; e < 2048; e += 256) sm[e] = ws[SMEAN_WS + e] * (1.f / HWSZ);
  __syncthreads();
  for (int e = t; e < 512; e += 256) {
    int b = e >> 6, cr = e & 63;
    float a = b_se1[cr];
    for (int c = 0; c < 256; c++) a += sm[b * 256 + c] * w_se1[cr * 256 + c];
    s1[e] = fmaxf(a, 0.f);
  }
  __syncthreads();
  for (int e = t; e < 2048; e += 256) {
    int b = e >> 8, c = e & 255;
    float a = b_se2[c];
    for (int cr = 0; cr < 64; cr++) a += s1[b * 64 + cr] * w_se2[c * 64 + cr];
    ws[SSCALE_WS + e] = 1.f / (1.f + expf(-a));
  }
}

// ---------------- k5: final combine: out = f*s*m + x ----------------
__global__ __launch_bounds__(256) void k5_final(const float* __restrict__ x,
                                                const float* __restrict__ ws,
                                                float* __restrict__ out) {
  const ushort* mws = (const ushort*)(ws + M_WS);
  int i4 = blockIdx.x * 256 + threadIdx.x;
  const int total = B_ * C_ * HWSZ / 4;
  for (; i4 < total; i4 += gridDim.x * 256) {
    int i = i4 * 4;
    int bc = i >> 12;
    float s = ws[SSCALE_WS + bc];
    float4 f = *(const float4*)&out[i];
    uint2 mu = *(const uint2*)&mws[i];
    float4 xv = *(const float4*)&x[i];
    float4 r;
    r.x = f.x * s * bff((ushort)(mu.x & 0xffffu)) + xv.x;
    r.y = f.y * s * bff((ushort)(mu.x >> 16)) + xv.y;
    r.z = f.z * s * bff((ushort)(mu.y & 0xffffu)) + xv.z;
    r.w = f.w * s * bff((ushort)(mu.y >> 16)) + xv.w;
    *(float4*)&out[i] = r;
  }
}

extern "C" void kernel_launch(void* const* d_in, const int* in_sizes, int n_in,
                              void* d_out, int out_size, void* d_ws, size_t ws_size,
                              hipStream_t stream) {
  const float* x      = (const float*)d_in[0];
  const float* w_off  = (const float*)d_in[1];
  const float* b_off  = (const float*)d_in[2];
  const float* w_mod  = (const float*)d_in[3];
  const float* b_mod  = (const float*)d_in[4];
  const float* w_reg  = (const float*)d_in[5];
  const float* b_reg  = (const float*)d_in[6];
  const float* w_se1  = (const float*)d_in[7];
  const float* b_se1  = (const float*)d_in[8];
  const float* w_se2  = (const float*)d_in[9];
  const float* b_se2  = (const float*)d_in[10];
  const float* w_mask = (const float*)d_in[11];
  const float* b_mask = (const float*)d_in[12];
  float* out = (float*)d_out;
  float* ws  = (float*)d_ws;

  k0_weights<<<dim3(2856), dim3(256), 0, stream>>>(w_reg, w_mask, w_off, w_mod, ws);
  k0b_nhwc<<<dim3(512), dim3(256), 0, stream>>>(x, ws);
  k2_fused<<<dim3(512), dim3(512), 0, stream>>>(b_off, b_mod, b_reg, b_mask, ws, out);
  k4_se<<<dim3(1), dim3(256), 0, stream>>>(w_se1, b_se1, w_se2, b_se2, ws);
  k5_final<<<dim3(2048), dim3(256), 0, stream>>>(x, ws, out);
}

// Round 10
// 210.397 us; speedup vs baseline: 1.6852x; 1.1360x over previous
//
#include <hip/hip_runtime.h>
#include <math.h>

#define HWSZ 4096
#define C_ 256
#define B_ 8

// ws layout (float offsets)
#define M_WS      0          // mask bf16: 8*256*4096 ushort = 4194304 floats
#define XB_WS     4194304    // x bf16 NHWC [b][hw][c]: 4194304 floats
#define WT2_WS    8388608    // (10*65536 + 9*32*256) ushort
#define SMEAN_WS  8753152    // 2048 (f channel sums)
#define SSCALE_WS 8755200    // 2048

typedef __attribute__((ext_vector_type(8))) short short8;
typedef __attribute__((ext_vector_type(4))) float f32x4;

__device__ __forceinline__ uint bfr(float a) {  // f32 -> bf16 bits (RNE)
  uint u = __float_as_uint(a);
  return (u + 0x7fffu + ((u >> 16) & 1u)) >> 16;
}
__device__ __forceinline__ uint pk2(float a, float b) { return bfr(a) | (bfr(b) << 16); }
__device__ __forceinline__ float bff(ushort u) { return __uint_as_float((uint)u << 16); }
__device__ __forceinline__ float lo16(uint u) { return __uint_as_float(u << 16); }
__device__ __forceinline__ float hi16(uint u) { return __uint_as_float(u & 0xffff0000u); }

// ---------------- k0: weights -> bf16 (+ zero smean) ----------------
__global__ __launch_bounds__(256) void k0_weights(
    const float* __restrict__ w_reg, const float* __restrict__ w_mask,
    const float* __restrict__ w_off, const float* __restrict__ w_mod,
    float* __restrict__ ws) {
  int i = blockIdx.x * 256 + threadIdx.x;
  const int nwt = 10 * 65536;
  const int total = nwt + 9 * 32 * 256;   // 729088
  if (i >= total) {
    int z = i - total;
    if (z < 2048) ws[SMEAN_WS + z] = 0.f;
    return;
  }
  float v;
  if (i < 9 * 65536) {
    int kk = i >> 16, o = (i >> 8) & 255, c = i & 255;
    v = w_reg[(o * C_ + c) * 9 + kk];
  } else if (i < nwt) {
    v = w_mask[i - 9 * 65536];
  } else {
    int e = i - nwt;
    int s = e >> 13, r = e & 8191;
    int o2 = r >> 8, c = r & 255;
    if (o2 < 18)      v = w_off[(o2 * C_ + c) * 9 + s];
    else if (o2 < 27) v = w_mod[((o2 - 18) * C_ + c) * 9 + s];
    else              v = 0.f;
  }
  ((ushort*)(ws + WT2_WS))[i] = (ushort)bfr(v);
}

// ---------------- k0b: x NCHW f32 -> NHWC bf16 ----------------
__global__ __launch_bounds__(256) void k0b_nhwc(const float* __restrict__ x,
                                                float* __restrict__ ws) {
  __shared__ float tile[64][65];
  int b = blockIdx.x >> 6, hw0 = (blockIdx.x & 63) << 6;
  int t = threadIdx.x;
  uint* xb = (uint*)(ws + XB_WS) + ((size_t)b << 19);
  int rr = t >> 6, cc = t & 63;
  int e = t & 7, hwp = t >> 3;
  for (int cg = 0; cg < 4; cg++) {
    __syncthreads();
    const float* xp = x + ((size_t)(b * 256 + cg * 64 + rr)) * HWSZ + hw0 + cc;
    #pragma unroll
    for (int r0 = 0; r0 < 64; r0 += 4)
      tile[r0 + rr][cc] = xp[(size_t)r0 * HWSZ];
    __syncthreads();
    #pragma unroll
    for (int h2 = 0; h2 < 2; h2++) {
      int hw_l = h2 * 32 + hwp;
      int c2 = e * 8;
      uint4 val;
      val.x = pk2(tile[c2][hw_l], tile[c2 + 1][hw_l]);
      val.y = pk2(tile[c2 + 2][hw_l], tile[c2 + 3][hw_l]);
      val.z = pk2(tile[c2 + 4][hw_l], tile[c2 + 5][hw_l]);
      val.w = pk2(tile[c2 + 6][hw_l], tile[c2 + 7][hw_l]);
      *(uint4*)&xb[(size_t)(hw0 + hw_l) * 128 + cg * 32 + e * 4] = val;
    }
  }
}

// ---------------- k2: round-4 structure + dbuf vbuf, ONE barrier per tap ----------------
// 512 thr (8 waves) per (b,h). Per tap: GEMM(vb[cur]) -> gather kk+1 -> write vb[nxt] -> barrier.
// WAR-safe: vb[cur] rewritten only at kk+2, after the kk+1 barrier. Nothing held across barriers.
// Reg budget: acc[2][4]=32 AGPR + ~64 VGPR = 96 <= 128 cap from (512,4).
__global__ __launch_bounds__(512, 4) void k2_fused(
    const float* __restrict__ b_off, const float* __restrict__ b_mod,
    const float* __restrict__ b_reg, const float* __restrict__ b_mask,
    float* __restrict__ ws, float* __restrict__ out) {
  __shared__ uint vb[2][64 * 128];     // 2 x 32 KB
  __shared__ float offmod[27 * 64];    // 6.75 KB  (total 71 KB -> 2 blocks/CU)

  int bl = ((blockIdx.x & 7) << 6) | (blockIdx.x >> 3);   // XCD k -> image k
  int b = bl >> 6, h = bl & 63;
  int t = threadIdx.x;
  int lane = t & 63, w = t >> 6;
  const int hwid = t >> 5;                   // half-wave id 0..15
  const int cl = lane & 31;                  // channel chunk (8 ch)
  const ushort* xb2 = (const ushort*)(ws + XB_WS) + ((size_t)b << 20);
  const ushort* wt2 = (const ushort*)(ws + WT2_WS);
  const ushort* wom = wt2 + 10 * 65536;
  const int fr = lane & 15, fq = lane >> 4;

  auto widx = [&](int n) -> uint {
    return (uint)n * 128u + (((uint)cl * 4u) ^ ((uint)(n & 7) << 2));
  };
  auto makeRecs = [&](int kk, int nl, float* wg, int* ix) {
    float dy = offmod[(2 * kk) * 64 + nl];
    float dx = offmod[(2 * kk + 1) * 64 + nl];
    float md = offmod[(18 + kk) * 64 + nl];
    float py = (float)(h + kk / 3 - 1) + dy;
    float px = (float)(nl + kk % 3 - 1) + dx;
    float fy = floorf(py), fx = floorf(px);
    float ly = py - fy, lx = px - fx;
    int y0 = (int)fy, x0 = (int)fx;
    int y1 = y0 + 1, x1 = x0 + 1;
    float vy0 = ((unsigned)y0 < 64u) ? 1.f : 0.f;
    float vy1 = ((unsigned)y1 < 64u) ? 1.f : 0.f;
    float vx0 = ((unsigned)x0 < 64u) ? 1.f : 0.f;
    float vx1 = ((unsigned)x1 < 64u) ? 1.f : 0.f;
    int cy0 = min(max(y0, 0), 63), cy1 = min(max(y1, 0), 63);
    int cx0 = min(max(x0, 0), 63), cx1 = min(max(x1, 0), 63);
    ix[0] = cy0 * 64 + cx0; wg[0] = (1.f - ly) * (1.f - lx) * md * vy0 * vx0;
    ix[1] = cy0 * 64 + cx1; wg[1] = (1.f - ly) * lx * md * vy0 * vx1;
    ix[2] = cy1 * 64 + cx0; wg[2] = ly * (1.f - lx) * md * vy1 * vx0;
    ix[3] = cy1 * 64 + cx1; wg[3] = ly * lx * md * vy1 * vx1;
  };
  auto gatherTap = [&](int kk, uint buf) {   // deform tap kk -> vb[buf]
    #pragma unroll
    for (int p = 0; p < 4; p++) {
      int n = p * 16 + hwid;
      float wg[4]; int ix[4];
      makeRecs(kk, n, wg, ix);
      float a0 = 0.f, a1 = 0.f, a2 = 0.f, a3 = 0.f, a4 = 0.f, a5 = 0.f, a6 = 0.f, a7 = 0.f;
      #pragma unroll
      for (int cr = 0; cr < 4; cr++) {
        uint4 dd = *(const uint4*)(xb2 + (size_t)ix[cr] * 256 + cl * 8);
        float wv = wg[cr];
        a0 = fmaf(wv, lo16(dd.x), a0); a1 = fmaf(wv, hi16(dd.x), a1);
        a2 = fmaf(wv, lo16(dd.y), a2); a3 = fmaf(wv, hi16(dd.y), a3);
        a4 = fmaf(wv, lo16(dd.z), a4); a5 = fmaf(wv, hi16(dd.z), a5);
        a6 = fmaf(wv, lo16(dd.w), a6); a7 = fmaf(wv, hi16(dd.w), a7);
      }
      *(uint4*)&vb[buf][widx(n)] =
          make_uint4(pk2(a0, a1), pk2(a2, a3), pk2(a4, a5), pk2(a6, a7));
    }
  };
  auto gatherShift = [&](int s, uint buf) {  // im2col shift s -> vb[buf]
    int row = h + s / 3 - 1;
    #pragma unroll
    for (int p = 0; p < 4; p++) {
      int n = p * 16 + hwid;
      int col = n + s % 3 - 1;
      uint4 v = make_uint4(0, 0, 0, 0);
      if (((unsigned)row < 64u) && ((unsigned)col < 64u))
        v = *(const uint4*)(xb2 + ((size_t)(row * 64 + col)) * 256 + cl * 8);
      *(uint4*)&vb[buf][widx(n)] = v;
    }
  };
  auto gatherMask = [&](uint buf) {          // plain row -> vb[buf]
    #pragma unroll
    for (int p = 0; p < 4; p++) {
      int n = p * 16 + hwid;
      uint4 v = *(const uint4*)(xb2 + ((size_t)(h * 64 + n)) * 256 + cl * 8);
      *(uint4*)&vb[buf][widx(n)] = v;
    }
  };

  // ======== Phase A: off/mod conv, 9 shifts, dbuf single-barrier ========
  f32x4 aom = (f32x4)0.f;
  const int m0 = w >> 2, nt0 = w & 3;
  gatherShift(0, 0);
  __syncthreads();
  for (int s = 0; s < 9; s++) {
    const uint cur = s & 1;
    const ushort* wp = wom + (size_t)s * 8192;
    for (int ks = 0; ks < 8; ks++) {
      short8 af = *(const short8*)(wp + (m0 * 16 + fr) * 256 + ks * 32 + fq * 8);
      int bn = nt0 * 16 + fr;
      uint idx = (uint)bn * 128u + (((uint)(ks * 16 + fq * 4)) ^ ((uint)(bn & 7) << 2));
      short8 bf = *(const short8*)&vb[cur][idx];
      aom = __builtin_amdgcn_mfma_f32_16x16x32_bf16(af, bf, aom, 0, 0, 0);
    }
    if (s < 8) gatherShift(s + 1, cur ^ 1);
    __syncthreads();
  }
  #pragma unroll
  for (int r = 0; r < 4; r++) {
    int o = m0 * 16 + fq * 4 + r;
    int nn = nt0 * 16 + fr;
    if (o < 18) {
      offmod[o * 64 + nn] = aom[r] + b_off[o];
    } else if (o < 27) {
      float v = aom[r] + b_mod[o - 18];
      offmod[o * 64 + nn] = 2.f / (1.f + expf(-v));
    }
  }
  __syncthreads();

  // ======== Phase B: 9 deform taps + mask tap, dbuf single-barrier ========
  f32x4 acc[2][4];
  #pragma unroll
  for (int mt = 0; mt < 2; mt++)
    #pragma unroll
    for (int nt = 0; nt < 4; nt++) acc[mt][nt] = (f32x4)0.f;
  const int o0 = w << 5;
  float* sme = ws + SMEAN_WS + b * 256;
  ushort* mws = (ushort*)(ws + M_WS);

  gatherTap(0, 0);
  __syncthreads();

  for (int kk = 0; kk < 10; kk++) {
    const uint cur = kk & 1;
    const ushort* wtap = wt2 + (size_t)kk * 65536;
    for (int ks = 0; ks < 8; ks++) {
      short8 af0 = *(const short8*)(wtap + (o0 + fr) * 256 + ks * 32 + fq * 8);
      short8 af1 = *(const short8*)(wtap + (o0 + 16 + fr) * 256 + ks * 32 + fq * 8);
      #pragma unroll
      for (int nt = 0; nt < 4; nt++) {
        int bn = nt * 16 + fr;
        uint idx = (uint)bn * 128u + (((uint)(ks * 16 + fq * 4)) ^ ((uint)(bn & 7) << 2));
        short8 bf = *(const short8*)&vb[cur][idx];
        acc[0][nt] = __builtin_amdgcn_mfma_f32_16x16x32_bf16(af0, bf, acc[0][nt], 0, 0, 0);
        acc[1][nt] = __builtin_amdgcn_mfma_f32_16x16x32_bf16(af1, bf, acc[1][nt], 0, 0, 0);
      }
    }
    // f epilogue after tap 8 GEMM (deform conv complete)
    if (kk == 8) {
      #pragma unroll
      for (int mt = 0; mt < 2; mt++)
        #pragma unroll
        for (int r = 0; r < 4; r++) {
          int o = o0 + mt * 16 + fq * 4 + r;
          float bo = b_reg[o];
          float* op = out + (size_t)(b * C_ + o) * HWSZ + h * 64;
          float so = 0.f;
          #pragma unroll
          for (int nt = 0; nt < 4; nt++) {
            float fv = acc[mt][nt][r] + bo;
            op[nt * 16 + fr] = fv;
            so += fv;
            acc[mt][nt][r] = 0.f;
          }
          so += __shfl_xor(so, 1);
          so += __shfl_xor(so, 2);
          so += __shfl_xor(so, 4);
          so += __shfl_xor(so, 8);
          if (fr == 0) atomicAdd(&sme[o], so);
        }
    }
    if (kk < 8)       gatherTap(kk + 1, cur ^ 1);
    else if (kk == 8) gatherMask(cur ^ 1);
    if (kk < 9) __syncthreads();
  }

  // mask epilogue
  #pragma unroll
  for (int mt = 0; mt < 2; mt++)
    #pragma unroll
    for (int r = 0; r < 4; r++) {
      int o = o0 + mt * 16 + fq * 4 + r;
      float bm = b_mask[o];
      ushort* mp = mws + (size_t)(b * C_ + o) * HWSZ + h * 64;
      #pragma unroll
      for (int nt = 0; nt < 4; nt++) {
        float mv = fminf(fmaxf((acc[mt][nt][r] + bm) * (1.f / 6.f) + 0.5f, 0.f), 1.f);
        mp[nt * 16 + fr] = (ushort)bfr(mv);
      }
    }
}

// ---------------- k4: SE MLP (reads channel SUMS) ----------------
__global__ __launch_bounds__(256) void k4_se(
    const float* __restrict__ w_se1, const float* __restrict__ b_se1,
    const float* __restrict__ w_se2, const float* __restrict__ b_se2,
    float* __restrict__ ws) {
  __shared__ float sm[2048];
  __shared__ float s1[512];
  int t = threadIdx.x;
  for (int e = t; e < 2048; e += 256) sm[e] = ws[SMEAN_WS + e] * (1.f / HWSZ);
  __syncthreads();
  for (int e = t; e < 512; e += 256) {
    int b = e >> 6, cr = e & 63;
    float a = b_se1[cr];
    for (int c = 0; c < 256; c++) a += sm[b * 256 + c] * w_se1[cr * 256 + c];
    s1[e] = fmaxf(a, 0.f);
  }
  __syncthreads();
  for (int e = t; e < 2048; e += 256) {
    int b = e >> 8, c = e & 255;
    float a = b_se2[c];
    for (int cr = 0; cr < 64; cr++) a += s1[b * 64 + cr] * w_se2[c * 64 + cr];
    ws[SSCALE_WS + e] = 1.f / (1.f + expf(-a));
  }
}

// ---------------- k5: final combine: out = f*s*m + x ----------------
__global__ __launch_bounds__(256) void k5_final(const float* __restrict__ x,
                                                const float* __restrict__ ws,
                                                float* __restrict__ out) {
  const ushort* mws = (const ushort*)(ws + M_WS);
  int i4 = blockIdx.x * 256 + threadIdx.x;
  const int total = B_ * C_ * HWSZ / 4;
  for (; i4 < total; i4 += gridDim.x * 256) {
    int i = i4 * 4;
    int bc = i >> 12;
    float s = ws[SSCALE_WS + bc];
    float4 f = *(const float4*)&out[i];
    uint2 mu = *(const uint2*)&mws[i];
    float4 xv = *(const float4*)&x[i];
    float4 r;
    r.x = f.x * s * bff((ushort)(mu.x & 0xffffu)) + xv.x;
    r.y = f.y * s * bff((ushort)(mu.x >> 16)) + xv.y;
    r.z = f.z * s * bff((ushort)(mu.y & 0xffffu)) + xv.z;
    r.w = f.w * s * bff((ushort)(mu.y >> 16)) + xv.w;
    *(float4*)&out[i] = r;
  }
}

extern "C" void kernel_launch(void* const* d_in, const int* in_sizes, int n_in,
                              void* d_out, int out_size, void* d_ws, size_t ws_size,
                              hipStream_t stream) {
  const float* x      = (const float*)d_in[0];
  const float* w_off  = (const float*)d_in[1];
  const float* b_off  = (const float*)d_in[2];
  const float* w_mod  = (const float*)d_in[3];
  const float* b_mod  = (const float*)d_in[4];
  const float* w_reg  = (const float*)d_in[5];
  const float* b_reg  = (const float*)d_in[6];
  const float* w_se1  = (const float*)d_in[7];
  const float* b_se1  = (const float*)d_in[8];
  const float* w_se2  = (const float*)d_in[9];
  const float* b_se2  = (const float*)d_in[10];
  const float* w_mask = (const float*)d_in[11];
  const float* b_mask = (const float*)d_in[12];
  float* out = (float*)d_out;
  float* ws  = (float*)d_ws;

  k0_weights<<<dim3(2856), dim3(256), 0, stream>>>(w_reg, w_mask, w_off, w_mod, ws);
  k0b_nhwc<<<dim3(512), dim3(256), 0, stream>>>(x, ws);
  k2_fused<<<dim3(512), dim3(512), 0, stream>>>(b_off, b_mod, b_reg, b_mask, ws, out);
  k4_se<<<dim3(1), dim3(256), 0, stream>>>(w_se1, b_se1, w_se2, b_se2, ws);
  k5_final<<<dim3(2048), dim3(256), 0, stream>>>(x, ws, out);
}

// Round 11
// 194.821 us; speedup vs baseline: 1.8199x; 1.0799x over previous
//
#include <hip/hip_runtime.h>
#include <math.h>

#define HWSZ 4096
#define C_ 256
#define B_ 8

// ws layout (float offsets)
#define M_WS      0          // mask bf16: 8*256*4096 ushort = 4194304 floats
#define XB_WS     4194304    // x bf16 NHWC [b][hw][c]: 4194304 floats
#define WT2_WS    8388608    // (10*65536 + 9*32*256) ushort
#define SMEAN_WS  8753152    // 2048 (f channel sums)
#define SSCALE_WS 8755200    // 2048

typedef __attribute__((ext_vector_type(8))) short short8;
typedef __attribute__((ext_vector_type(4))) float f32x4;

__device__ __forceinline__ uint bfr(float a) {  // f32 -> bf16 bits (RNE)
  uint u = __float_as_uint(a);
  return (u + 0x7fffu + ((u >> 16) & 1u)) >> 16;
}
__device__ __forceinline__ uint pk2(float a, float b) { return bfr(a) | (bfr(b) << 16); }
__device__ __forceinline__ float bff(ushort u) { return __uint_as_float((uint)u << 16); }
__device__ __forceinline__ float lo16(uint u) { return __uint_as_float(u << 16); }
__device__ __forceinline__ float hi16(uint u) { return __uint_as_float(u & 0xffff0000u); }

// ---------------- k0: weights -> bf16 (+ zero smean) ----------------
__global__ __launch_bounds__(256) void k0_weights(
    const float* __restrict__ w_reg, const float* __restrict__ w_mask,
    const float* __restrict__ w_off, const float* __restrict__ w_mod,
    float* __restrict__ ws) {
  int i = blockIdx.x * 256 + threadIdx.x;
  const int nwt = 10 * 65536;
  const int total = nwt + 9 * 32 * 256;   // 729088
  if (i >= total) {
    int z = i - total;
    if (z < 2048) ws[SMEAN_WS + z] = 0.f;
    return;
  }
  float v;
  if (i < 9 * 65536) {
    int kk = i >> 16, o = (i >> 8) & 255, c = i & 255;
    v = w_reg[(o * C_ + c) * 9 + kk];
  } else if (i < nwt) {
    v = w_mask[i - 9 * 65536];
  } else {
    int e = i - nwt;
    int s = e >> 13, r = e & 8191;
    int o2 = r >> 8, c = r & 255;
    if (o2 < 18)      v = w_off[(o2 * C_ + c) * 9 + s];
    else if (o2 < 27) v = w_mod[((o2 - 18) * C_ + c) * 9 + s];
    else              v = 0.f;
  }
  ((ushort*)(ws + WT2_WS))[i] = (ushort)bfr(v);
}

// ---------------- k0b: x NCHW f32 -> NHWC bf16 ----------------
__global__ __launch_bounds__(256) void k0b_nhwc(const float* __restrict__ x,
                                                float* __restrict__ ws) {
  __shared__ float tile[64][65];
  int b = blockIdx.x >> 6, hw0 = (blockIdx.x & 63) << 6;
  int t = threadIdx.x;
  uint* xb = (uint*)(ws + XB_WS) + ((size_t)b << 19);
  int rr = t >> 6, cc = t & 63;
  int e = t & 7, hwp = t >> 3;
  for (int cg = 0; cg < 4; cg++) {
    __syncthreads();
    const float* xp = x + ((size_t)(b * 256 + cg * 64 + rr)) * HWSZ + hw0 + cc;
    #pragma unroll
    for (int r0 = 0; r0 < 64; r0 += 4)
      tile[r0 + rr][cc] = xp[(size_t)r0 * HWSZ];
    __syncthreads();
    #pragma unroll
    for (int h2 = 0; h2 < 2; h2++) {
      int hw_l = h2 * 32 + hwp;
      int c2 = e * 8;
      uint4 val;
      val.x = pk2(tile[c2][hw_l], tile[c2 + 1][hw_l]);
      val.y = pk2(tile[c2 + 2][hw_l], tile[c2 + 3][hw_l]);
      val.z = pk2(tile[c2 + 4][hw_l], tile[c2 + 5][hw_l]);
      val.w = pk2(tile[c2 + 6][hw_l], tile[c2 + 7][hw_l]);
      *(uint4*)&xb[(size_t)(hw0 + hw_l) * 128 + cg * 32 + e * 4] = val;
    }
  }
}

// ---------------- k2: fused kernel, compressed phase A (row-buffer reuse) ----------------
// 512 thr (8 waves) per (b,h). Phase A: 3 padded row-copies + 3 GEMM epochs run all
// 9 shifts + mask conv (reads row-h buffer). Phase B: r10's dbuf 9-tap loop.
// Regs: peak 32 AGPR + ~60 VGPR = 96 <= 128 cap (512,4). LDS 76.6 KB -> 2 blocks/CU.
__global__ __launch_bounds__(512, 4) void k2_fused(
    const float* __restrict__ b_off, const float* __restrict__ b_mod,
    const float* __restrict__ b_reg, const float* __restrict__ b_mask,
    float* __restrict__ ws, float* __restrict__ out) {
  __shared__ uint vbraw[2][66 * 128];   // 67.6 KB: padded rows (A) / dbuf taps (B)
  __shared__ float omrf[9 * 64 * 4];    // 9 KB: per-(tap,n) float4 {dy,dx,md,-}

  int bl = ((blockIdx.x & 7) << 6) | (blockIdx.x >> 3);   // XCD k -> image k
  int b = bl >> 6, h = bl & 63;
  int t = threadIdx.x;
  int lane = t & 63, w = t >> 6;
  const int hwid = t >> 5;                   // half-wave id 0..15
  const int cl = lane & 31;                  // channel chunk (8 ch)
  const ushort* xb2 = (const ushort*)(ws + XB_WS) + ((size_t)b << 20);
  const ushort* wt2 = (const ushort*)(ws + WT2_WS);
  const ushort* wom = wt2 + 10 * 65536;
  const int fr = lane & 15, fq = lane >> 4;

  auto widxP = [&](int pcol) -> uint {
    return (uint)pcol * 128u + (((uint)cl * 4u) ^ ((uint)(pcol & 7) << 2));
  };
  // stage one padded x row into vbraw[buf]: pcol 0..65 <-> col pcol-1 (zero pad at edges)
  auto stageRow = [&](int row, int buf) {
    bool rv = ((unsigned)row < 64u);
    #pragma unroll
    for (int p = 0; p < 4; p++) {
      int pcol = p * 16 + hwid;
      int col = pcol - 1;
      uint4 v = make_uint4(0, 0, 0, 0);
      if (rv && ((unsigned)col < 64u))
        v = *(const uint4*)(xb2 + ((size_t)(row * 64 + col)) * 256 + cl * 8);
      *(uint4*)&vbraw[buf][widxP(pcol)] = v;
    }
    if (hwid < 2) {
      int pcol = 64 + hwid;
      int col = pcol - 1;     // 63 (valid), 64 (pad)
      uint4 v = make_uint4(0, 0, 0, 0);
      if (rv && col < 64)
        v = *(const uint4*)(xb2 + ((size_t)(row * 64 + col)) * 256 + cl * 8);
      *(uint4*)&vbraw[buf][widxP(pcol)] = v;
    }
  };
  auto makeRecs = [&](int kk, int nl, float* wg, int* ix) {
    const float4 rec = *(const float4*)&omrf[kk * 256 + nl * 4];
    float dy = rec.x, dx = rec.y, md = rec.z;
    float py = (float)(h + kk / 3 - 1) + dy;
    float px = (float)(nl + kk % 3 - 1) + dx;
    float fy = floorf(py), fx = floorf(px);
    float ly = py - fy, lx = px - fx;
    int y0 = (int)fy, x0 = (int)fx;
    int y1 = y0 + 1, x1 = x0 + 1;
    float vy0 = ((unsigned)y0 < 64u) ? 1.f : 0.f;
    float vy1 = ((unsigned)y1 < 64u) ? 1.f : 0.f;
    float vx0 = ((unsigned)x0 < 64u) ? 1.f : 0.f;
    float vx1 = ((unsigned)x1 < 64u) ? 1.f : 0.f;
    int cy0 = min(max(y0, 0), 63), cy1 = min(max(y1, 0), 63);
    int cx0 = min(max(x0, 0), 63), cx1 = min(max(x1, 0), 63);
    ix[0] = cy0 * 64 + cx0; wg[0] = (1.f - ly) * (1.f - lx) * md * vy0 * vx0;
    ix[1] = cy0 * 64 + cx1; wg[1] = (1.f - ly) * lx * md * vy0 * vx1;
    ix[2] = cy1 * 64 + cx0; wg[2] = ly * (1.f - lx) * md * vy1 * vx0;
    ix[3] = cy1 * 64 + cx1; wg[3] = ly * lx * md * vy1 * vx1;
  };
  auto gatherTap = [&](int kk, int buf) {
    #pragma unroll
    for (int p = 0; p < 4; p++) {
      int n = p * 16 + hwid;
      float wg[4]; int ix[4];
      makeRecs(kk, n, wg, ix);
      float a0 = 0.f, a1 = 0.f, a2 = 0.f, a3 = 0.f, a4 = 0.f, a5 = 0.f, a6 = 0.f, a7 = 0.f;
      #pragma unroll
      for (int cr = 0; cr < 4; cr++) {
        uint4 dd = *(const uint4*)(xb2 + (size_t)ix[cr] * 256 + cl * 8);
        float wv = wg[cr];
        a0 = fmaf(wv, lo16(dd.x), a0); a1 = fmaf(wv, hi16(dd.x), a1);
        a2 = fmaf(wv, lo16(dd.y), a2); a3 = fmaf(wv, hi16(dd.y), a3);
        a4 = fmaf(wv, lo16(dd.z), a4); a5 = fmaf(wv, hi16(dd.z), a5);
        a6 = fmaf(wv, lo16(dd.w), a6); a7 = fmaf(wv, hi16(dd.w), a7);
      }
      *(uint4*)&vbraw[buf][widxP(n)] =
          make_uint4(pk2(a0, a1), pk2(a2, a3), pk2(a4, a5), pk2(a6, a7));
    }
  };

  // ======== Phase A: 3 row-copies, 3 GEMM epochs (9 shifts) + mask conv ========
  f32x4 aom = (f32x4)0.f;
  const int m0 = w >> 2, nt0 = w & 3;
  const int o0 = w << 5;
  f32x4 acc[2][4];   // mask conv first, then reused for deform
  #pragma unroll
  for (int mt = 0; mt < 2; mt++)
    #pragma unroll
    for (int nt = 0; nt < 4; nt++) acc[mt][nt] = (f32x4)0.f;
  ushort* mws = (ushort*)(ws + M_WS);
  float* sme = ws + SMEAN_WS + b * 256;

  stageRow(h - 1, 0);
  __syncthreads();
  for (int e = 0; e < 3; e++) {
    const int buf = (e == 1) ? 1 : 0;   // e0: row h-1, e1: row h, e2: row h+1
    {
      const int bnA = nt0 * 16 + fr;
      #pragma unroll
      for (int s3 = 0; s3 < 3; s3++) {
        int s = e * 3 + s3;
        const ushort* wp = wom + (size_t)s * 8192;
        int pcol = bnA + s3;
        for (int ks = 0; ks < 8; ks++) {
          short8 af = *(const short8*)(wp + (m0 * 16 + fr) * 256 + ks * 32 + fq * 8);
          uint idx = (uint)pcol * 128u + (((uint)(ks * 16 + fq * 4)) ^ ((uint)(pcol & 7) << 2));
          short8 bf = *(const short8*)&vbraw[buf][idx];
          aom = __builtin_amdgcn_mfma_f32_16x16x32_bf16(af, bf, aom, 0, 0, 0);
        }
      }
    }
    if (e == 1) {   // mask 1x1 conv rides the row-h buffer (pcol = n+1)
      const ushort* wt9 = wt2 + (size_t)9 * 65536;
      __builtin_amdgcn_s_setprio(1);
      for (int ks = 0; ks < 8; ks++) {
        short8 af0 = *(const short8*)(wt9 + (o0 + fr) * 256 + ks * 32 + fq * 8);
        short8 af1 = *(const short8*)(wt9 + (o0 + 16 + fr) * 256 + ks * 32 + fq * 8);
        #pragma unroll
        for (int nt = 0; nt < 4; nt++) {
          int pcol = nt * 16 + fr + 1;
          uint idx = (uint)pcol * 128u + (((uint)(ks * 16 + fq * 4)) ^ ((uint)(pcol & 7) << 2));
          short8 bf = *(const short8*)&vbraw[1][idx];
          acc[0][nt] = __builtin_amdgcn_mfma_f32_16x16x32_bf16(af0, bf, acc[0][nt], 0, 0, 0);
          acc[1][nt] = __builtin_amdgcn_mfma_f32_16x16x32_bf16(af1, bf, acc[1][nt], 0, 0, 0);
        }
      }
      __builtin_amdgcn_s_setprio(0);
    }
    if (e == 0)      stageRow(h, 1);
    else if (e == 1) stageRow(h + 1, 0);
    else {
      // mask epilogue (acc holds mask conv; reset after)
      #pragma unroll
      for (int mt = 0; mt < 2; mt++)
        #pragma unroll
        for (int r = 0; r < 4; r++) {
          int o = o0 + mt * 16 + fq * 4 + r;
          float bm = b_mask[o];
          ushort* mp = mws + (size_t)(b * C_ + o) * HWSZ + h * 64;
          #pragma unroll
          for (int nt = 0; nt < 4; nt++) {
            float mv = fminf(fmaxf((acc[mt][nt][r] + bm) * (1.f / 6.f) + 0.5f, 0.f), 1.f);
            mp[nt * 16 + fr] = (ushort)bfr(mv);
            acc[mt][nt][r] = 0.f;
          }
        }
      // aom epilogue -> packed records omr[kk][n] = {dy, dx, md, -}
      #pragma unroll
      for (int r = 0; r < 4; r++) {
        int o = m0 * 16 + fq * 4 + r;
        int nn = nt0 * 16 + fr;
        if (o < 18) {
          omrf[(o >> 1) * 256 + nn * 4 + (o & 1)] = aom[r] + b_off[o];
        } else if (o < 27) {
          float v = aom[r] + b_mod[o - 18];
          omrf[(o - 18) * 256 + nn * 4 + 2] = 2.f / (1.f + expf(-v));
        }
      }
    }
    __syncthreads();
  }

  // ======== Phase B: 9 deform taps, dbuf single-barrier (r10) ========
  gatherTap(0, 1);    // buf1 free (last read in epoch e=1)
  __syncthreads();
  for (int kk = 0; kk < 9; kk++) {
    const int cur = (kk & 1) ^ 1;
    const ushort* wtap = wt2 + (size_t)kk * 65536;
    __builtin_amdgcn_s_setprio(1);
    for (int ks = 0; ks < 8; ks++) {
      short8 af0 = *(const short8*)(wtap + (o0 + fr) * 256 + ks * 32 + fq * 8);
      short8 af1 = *(const short8*)(wtap + (o0 + 16 + fr) * 256 + ks * 32 + fq * 8);
      #pragma unroll
      for (int nt = 0; nt < 4; nt++) {
        int bn = nt * 16 + fr;
        uint idx = (uint)bn * 128u + (((uint)(ks * 16 + fq * 4)) ^ ((uint)(bn & 7) << 2));
        short8 bf = *(const short8*)&vbraw[cur][idx];
        acc[0][nt] = __builtin_amdgcn_mfma_f32_16x16x32_bf16(af0, bf, acc[0][nt], 0, 0, 0);
        acc[1][nt] = __builtin_amdgcn_mfma_f32_16x16x32_bf16(af1, bf, acc[1][nt], 0, 0, 0);
      }
    }
    __builtin_amdgcn_s_setprio(0);
    if (kk < 8) {
      gatherTap(kk + 1, cur ^ 1);
      __syncthreads();
    }
  }

  // f epilogue + fused SE partial sums
  #pragma unroll
  for (int mt = 0; mt < 2; mt++)
    #pragma unroll
    for (int r = 0; r < 4; r++) {
      int o = o0 + mt * 16 + fq * 4 + r;
      float bo = b_reg[o];
      float* op = out + (size_t)(b * C_ + o) * HWSZ + h * 64;
      float so = 0.f;
      #pragma unroll
      for (int nt = 0; nt < 4; nt++) {
        float fv = acc[mt][nt][r] + bo;
        op[nt * 16 + fr] = fv;
        so += fv;
      }
      so += __shfl_xor(so, 1);
      so += __shfl_xor(so, 2);
      so += __shfl_xor(so, 4);
      so += __shfl_xor(so, 8);
      if (fr == 0) atomicAdd(&sme[o], so);
    }
}

// ---------------- k4: SE MLP, one block per batch ----------------
__global__ __launch_bounds__(256) void k4_se(
    const float* __restrict__ w_se1, const float* __restrict__ b_se1,
    const float* __restrict__ w_se2, const float* __restrict__ b_se2,
    float* __restrict__ ws) {
  __shared__ float sm[256];
  __shared__ float s1[64];
  int b = blockIdx.x;
  int t = threadIdx.x;
  sm[t] = ws[SMEAN_WS + b * 256 + t] * (1.f / HWSZ);
  __syncthreads();
  if (t < 64) {
    float a = b_se1[t];
    for (int c = 0; c < 256; c++) a += sm[c] * w_se1[t * 256 + c];
    s1[t] = fmaxf(a, 0.f);
  }
  __syncthreads();
  {
    float a = b_se2[t];
    for (int cr = 0; cr < 64; cr++) a += s1[cr] * w_se2[t * 64 + cr];
    ws[SSCALE_WS + b * 256 + t] = 1.f / (1.f + expf(-a));
  }
}

// ---------------- k5: final combine: out = f*s*m + x ----------------
__global__ __launch_bounds__(256) void k5_final(const float* __restrict__ x,
                                                const float* __restrict__ ws,
                                                float* __restrict__ out) {
  const ushort* mws = (const ushort*)(ws + M_WS);
  int i4 = blockIdx.x * 256 + threadIdx.x;
  const int total = B_ * C_ * HWSZ / 4;
  for (; i4 < total; i4 += gridDim.x * 256) {
    int i = i4 * 4;
    int bc = i >> 12;
    float s = ws[SSCALE_WS + bc];
    float4 f = *(const float4*)&out[i];
    uint2 mu = *(const uint2*)&mws[i];
    float4 xv = *(const float4*)&x[i];
    float4 r;
    r.x = f.x * s * bff((ushort)(mu.x & 0xffffu)) + xv.x;
    r.y = f.y * s * bff((ushort)(mu.x >> 16)) + xv.y;
    r.z = f.z * s * bff((ushort)(mu.y & 0xffffu)) + xv.z;
    r.w = f.w * s * bff((ushort)(mu.y >> 16)) + xv.w;
    *(float4*)&out[i] = r;
  }
}

extern "C" void kernel_launch(void* const* d_in, const int* in_sizes, int n_in,
                              void* d_out, int out_size, void* d_ws, size_t ws_size,
                              hipStream_t stream) {
  const float* x      = (const float*)d_in[0];
  const float* w_off  = (const float*)d_in[1];
  const float* b_off  = (const float*)d_in[2];
  const float* w_mod  = (const float*)d_in[3];
  const float* b_mod  = (const float*)d_in[4];
  const float* w_reg  = (const float*)d_in[5];
  const float* b_reg  = (const float*)d_in[6];
  const float* w_se1  = (const float*)d_in[7];
  const float* b_se1  = (const float*)d_in[8];
  const float* w_se2  = (const float*)d_in[9];
  const float* b_se2  = (const float*)d_in[10];
  const float* w_mask = (const float*)d_in[11];
  const float* b_mask = (const float*)d_in[12];
  float* out = (float*)d_out;
  float* ws  = (float*)d_ws;

  k0_weights<<<dim3(2856), dim3(256), 0, stream>>>(w_reg, w_mask, w_off, w_mod, ws);
  k0b_nhwc<<<dim3(512), dim3(256), 0, stream>>>(x, ws);
  k2_fused<<<dim3(512), dim3(512), 0, stream>>>(b_off, b_mod, b_reg, b_mask, ws, out);
  k4_se<<<dim3(8), dim3(256), 0, stream>>>(w_se1, b_se1, w_se2, b_se2, ws);
  k5_final<<<dim3(2048), dim3(256), 0, stream>>>(x, ws, out);
}